// Round 10
// baseline (435.462 us; speedup 1.0000x reference)
//
#include <hip/hip_runtime.h>
#include <hip/hip_fp16.h>

#define F_IN 16
#define F_HID 64
#define NPG 4            // nodes per 8-lane group in aggpool
#define SCAN_CHUNK 1024
#define EPB 4096         // edges per radix block
#define BKN 1024         // nodes per coarse bucket (rel = 10 bits)

// Combined problem: both graphs concatenated. Node j in [0,2n): graph g=j/n.
// Edge e in [0,2E): graph g=e/E. Segment id = batch[g][..] + g*G.
// pairs word = (rel10 << 18) | src18   (2n = 200000 < 2^18)

// E and E2 are multiples of 4 (E = 1.6M), so int4 edge loads never straddle.
__device__ inline void load_edge4(const int* __restrict__ ei1, const int* __restrict__ ei2,
                                  int E, int n, int e4, int4& s4, int4& d4) {
    if (e4 < E) {
        s4 = *(const int4*)(ei1 + e4);
        d4 = *(const int4*)(ei1 + E + e4);
    } else {
        int eb = e4 - E;
        s4 = *(const int4*)(ei2 + eb);
        d4 = *(const int4*)(ei2 + E + eb);
        s4.x += n; s4.y += n; s4.z += n; s4.w += n;
        d4.x += n; d4.y += n; d4.z += n; d4.w += n;
    }
}

// ---- radix CSR build (no global atomics) ----------------------------------

// Pass A.1: per-block LDS histogram over coarse buckets -> count[bucket][blk]
__global__ void histA_kernel(const int* __restrict__ ei1, const int* __restrict__ ei2,
                             int E, int n, unsigned* __restrict__ count,
                             int nblkA, int NBK, int E2) {
    __shared__ unsigned hist[256];   // NBK <= 256
    for (int i = threadIdx.x; i < NBK; i += 256) hist[i] = 0;
    __syncthreads();
    int base = blockIdx.x * EPB;
    #pragma unroll
    for (int r = 0; r < EPB / 1024; ++r) {
        int e4 = base + r * 1024 + threadIdx.x * 4;
        if (e4 + 4 <= E2) {
            int4 s4, d4;
            load_edge4(ei1, ei2, E, n, e4, s4, d4);
            atomicAdd(&hist[d4.x >> 10], 1u);
            atomicAdd(&hist[d4.y >> 10], 1u);
            atomicAdd(&hist[d4.z >> 10], 1u);
            atomicAdd(&hist[d4.w >> 10], 1u);
        } else if (e4 < E2) {
            for (int e = e4; e < E2; ++e) {
                int d = (e < E) ? ei1[E + e] : (ei2[e] + n);
                atomicAdd(&hist[d >> 10], 1u);
            }
        }
    }
    __syncthreads();
    for (int i = threadIdx.x; i < NBK; i += 256)
        count[(size_t)i * nblkA + blockIdx.x] = hist[i];
}

__global__ void scan1_kernel(const unsigned* __restrict__ a, unsigned* __restrict__ bsum, int N) {
    __shared__ unsigned s[256];
    int base = blockIdx.x * SCAN_CHUNK;
    unsigned t = 0;
    for (int i = threadIdx.x; i < SCAN_CHUNK; i += 256) {
        int idx = base + i;
        if (idx < N) t += a[idx];
    }
    s[threadIdx.x] = t;
    __syncthreads();
    for (int o = 128; o > 0; o >>= 1) {
        if (threadIdx.x < o) s[threadIdx.x] += s[threadIdx.x + o];
        __syncthreads();
    }
    if (threadIdx.x == 0) bsum[blockIdx.x] = s[0];
}

__global__ void scan2_kernel(unsigned* __restrict__ bsum, int nb) {
    if (threadIdx.x == 0 && blockIdx.x == 0) {
        unsigned run = 0;
        for (int i = 0; i < nb; ++i) { unsigned v = bsum[i]; bsum[i] = run; run += v; }
    }
}

// generic in-place exclusive scan finalize
__global__ void scan3g_kernel(unsigned* __restrict__ a, const unsigned* __restrict__ bsum, int N) {
    __shared__ unsigned s[256];
    int tid = threadIdx.x;
    int base = blockIdx.x * SCAN_CHUNK;
    unsigned loc[4];
    unsigned t = 0;
    #pragma unroll
    for (int j = 0; j < 4; ++j) {
        int idx = base + tid * 4 + j;
        loc[j] = (idx < N) ? a[idx] : 0u;
        t += loc[j];
    }
    s[tid] = t;
    __syncthreads();
    for (int o = 1; o < 256; o <<= 1) {
        unsigned v = (tid >= o) ? s[tid - o] : 0u;
        __syncthreads();
        s[tid] += v;
        __syncthreads();
    }
    unsigned off = bsum[blockIdx.x] + s[tid] - t;
    #pragma unroll
    for (int j = 0; j < 4; ++j) {
        int idx = base + tid * 4 + j;
        if (idx < N) a[idx] = off;
        off += loc[j];
    }
}

// Pass A.2: place edges into pairs via LDS cursors (per-(block,bucket) runs
// are consecutive -> near-line-sized writes, zero global atomics).
__global__ void passA2_kernel(const int* __restrict__ ei1, const int* __restrict__ ei2,
                              int E, int n, const unsigned* __restrict__ cbase,
                              unsigned* __restrict__ pairs, int nblkA, int NBK, int E2) {
    __shared__ unsigned cur[256];
    for (int i = threadIdx.x; i < NBK; i += 256)
        cur[i] = cbase[(size_t)i * nblkA + blockIdx.x];
    __syncthreads();
    int base = blockIdx.x * EPB;
    #pragma unroll
    for (int r = 0; r < EPB / 1024; ++r) {
        int e4 = base + r * 1024 + threadIdx.x * 4;
        if (e4 + 4 <= E2) {
            int4 s4, d4;
            load_edge4(ei1, ei2, E, n, e4, s4, d4);
            unsigned p;
            p = atomicAdd(&cur[d4.x >> 10], 1u);
            pairs[p] = ((unsigned)(d4.x & 1023) << 18) | (unsigned)s4.x;
            p = atomicAdd(&cur[d4.y >> 10], 1u);
            pairs[p] = ((unsigned)(d4.y & 1023) << 18) | (unsigned)s4.y;
            p = atomicAdd(&cur[d4.z >> 10], 1u);
            pairs[p] = ((unsigned)(d4.z & 1023) << 18) | (unsigned)s4.z;
            p = atomicAdd(&cur[d4.w >> 10], 1u);
            pairs[p] = ((unsigned)(d4.w & 1023) << 18) | (unsigned)s4.w;
        } else if (e4 < E2) {
            for (int e = e4; e < E2; ++e) {
                int s = (e < E) ? ei1[e] : (ei2[e - E] + n);
                int d = (e < E) ? ei1[E + e] : (ei2[e] + n);
                unsigned p = atomicAdd(&cur[d >> 10], 1u);
                pairs[p] = ((unsigned)(d & 1023) << 18) | (unsigned)s;
            }
        }
    }
}

// Pass B: one block per bucket. From pairs: per-node degree (LDS), block scan
// -> row_start + dinv + prescaled fp16 xs; then place csr_src via LDS cursors.
__global__ void bucketB_kernel(const unsigned* __restrict__ pairs,
                               const unsigned* __restrict__ cbase,
                               const float* __restrict__ x1, const float* __restrict__ x2,
                               int* __restrict__ row_start, float* __restrict__ dinv,
                               __half* __restrict__ xs, int* __restrict__ csr_src,
                               int n, int n2, int E2, int nblkA, int NBK) {
    __shared__ unsigned cnt[BKN];
    __shared__ int cur[BKN];
    __shared__ unsigned s[256];
    int b = blockIdx.x;
    int nodebase = b * BKN;
    int nn = n2 - nodebase; if (nn > BKN) nn = BKN;
    unsigned begin = cbase[(size_t)b * nblkA];
    unsigned end = (b + 1 < NBK) ? cbase[(size_t)(b + 1) * nblkA] : (unsigned)E2;
    int t = threadIdx.x;

    for (int i = t; i < BKN; i += 256) cnt[i] = 0;
    __syncthreads();
    for (unsigned i = begin + t; i < end; i += 256)
        atomicAdd(&cnt[pairs[i] >> 18], 1u);
    __syncthreads();

    unsigned loc[4];
    unsigned tot = 0;
    #pragma unroll
    for (int j = 0; j < 4; ++j) { loc[j] = cnt[t * 4 + j]; tot += loc[j]; }
    s[t] = tot;
    __syncthreads();
    for (int o = 1; o < 256; o <<= 1) {
        unsigned v = (t >= o) ? s[t - o] : 0u;
        __syncthreads();
        s[t] += v;
        __syncthreads();
    }
    unsigned off = begin + s[t] - tot;
    #pragma unroll
    for (int j = 0; j < 4; ++j) {
        int i = t * 4 + j;
        if (i < nn) {
            int node = nodebase + i;
            row_start[node] = (int)off;
            cur[i] = (int)off;
            float di = rsqrtf((float)loc[j] + 1.0f);
            dinv[node] = di;
            const float* xr = (node < n) ? (x1 + (size_t)node * F_IN)
                                         : (x2 + (size_t)(node - n) * F_IN);
            const float4* xin = (const float4*)xr;
            union { float4 f4; __half2 h2[4]; } u;
            __half2* xo = (__half2*)(xs + (size_t)node * F_IN);
            #pragma unroll
            for (int c = 0; c < 2; ++c) {
                float4 v0 = xin[2 * c], v1 = xin[2 * c + 1];
                u.h2[0] = __float22half2_rn(make_float2(v0.x * di, v0.y * di));
                u.h2[1] = __float22half2_rn(make_float2(v0.z * di, v0.w * di));
                u.h2[2] = __float22half2_rn(make_float2(v1.x * di, v1.y * di));
                u.h2[3] = __float22half2_rn(make_float2(v1.z * di, v1.w * di));
                *(float4*)(xo + 4 * c) = u.f4;
            }
        }
        off += loc[j];
    }
    __syncthreads();
    for (unsigned i = begin + t; i < end; i += 256) {
        unsigned v = pairs[i];
        int pos = atomicAdd(&cur[v >> 18], 1);
        csr_src[pos] = (int)(v & 0x3FFFFu);
    }
    if (b == 0 && t == 0) row_start[n2] = E2;
}

// ---- fused gather+MLP / pool ----------------------------------------------

__device__ inline void acc_row2(float4& a, float2 r) {
    union { float2 f2; __half2 h2[2]; } u; u.f2 = r;
    float2 lo = __half22float2(u.h2[0]), hi = __half22float2(u.h2[1]);
    a.x += lo.x; a.y += lo.y; a.z += hi.x; a.w += hi.y;
}

__device__ inline void acc_row4(float4& a0, float4& a1, float4 r) {
    union { float4 f4; __half2 h2[4]; } u; u.f4 = r;
    float2 p0 = __half22float2(u.h2[0]), p1 = __half22float2(u.h2[1]);
    float2 p2 = __half22float2(u.h2[2]), p3 = __half22float2(u.h2[3]);
    a0.x += p0.x; a0.y += p0.y; a0.z += p1.x; a0.w += p1.y;
    a1.x += p2.x; a1.y += p2.y; a1.z += p3.x; a1.w += p3.y;
}

// Fused layer-1 gather + dense 2-layer MLP (W2 folded):
//   xagg = dinv*(sum_s xs[s] + xs[self])          (gather, 4 lanes/node)
//   hw   = (relu(xagg @ W1 + b1) * dinv) @ W2     (dense, LDS weights)
// 64 nodes/block; thread t: node m=t>>2, quarter jg=t&3.
__global__ __launch_bounds__(256) void aggmlp_kernel(
        const int* __restrict__ csr_src, const int* __restrict__ row_start,
        const __half* __restrict__ xs, const float* __restrict__ dinv,
        const float* __restrict__ W1, const float* __restrict__ b1,
        const float* __restrict__ W2, __half* __restrict__ hw, int n2) {
    __shared__ __align__(16) float w1[F_IN * F_HID];
    __shared__ __align__(16) float w2[F_HID * F_HID];
    __shared__ float b1s[F_HID];
    __shared__ __align__(16) float xl[64][20];
    __shared__ __align__(16) float h1s[64][68];
    int t = threadIdx.x;
    for (int i = t; i < F_IN * F_HID; i += 256) w1[i] = W1[i];
    for (int i = t; i < F_HID * F_HID; i += 256) w2[i] = W2[i];
    if (t < F_HID) b1s[t] = b1[t];

    int base = blockIdx.x * 64;
    int m = t >> 2, jg = t & 3, j0 = jg * 16;
    int node = base + m;
    bool valid = node < n2;
    float di = 0.0f;

    // gather phase: each of the node's 4 threads owns 4 of 16 features
    if (valid) {
        int start = row_start[node], end = row_start[node + 1];
        float4 acc = make_float4(0.f, 0.f, 0.f, 0.f);
        int e = start;
        for (; e + 4 <= end; e += 4) {
            int i0 = csr_src[e + 0], i1 = csr_src[e + 1];
            int i2 = csr_src[e + 2], i3 = csr_src[e + 3];
            float2 r0 = *(const float2*)(xs + (size_t)i0 * F_IN + jg * 4);
            float2 r1 = *(const float2*)(xs + (size_t)i1 * F_IN + jg * 4);
            float2 r2 = *(const float2*)(xs + (size_t)i2 * F_IN + jg * 4);
            float2 r3 = *(const float2*)(xs + (size_t)i3 * F_IN + jg * 4);
            acc_row2(acc, r0); acc_row2(acc, r1); acc_row2(acc, r2); acc_row2(acc, r3);
        }
        for (; e < end; ++e) {
            float2 r0 = *(const float2*)(xs + (size_t)csr_src[e] * F_IN + jg * 4);
            acc_row2(acc, r0);
        }
        float2 rs = *(const float2*)(xs + (size_t)node * F_IN + jg * 4);
        acc_row2(acc, rs);
        di = dinv[node];
        *(float4*)&xl[m][jg * 4] =
            make_float4(acc.x * di, acc.y * di, acc.z * di, acc.w * di);
    }
    __syncthreads();

    float acc[16];
    #pragma unroll
    for (int jj = 0; jj < 16; ++jj) acc[jj] = 0.0f;
    if (valid) {
        #pragma unroll
        for (int k = 0; k < F_IN; ++k) {
            float xv = xl[m][k];
            const float4* wp = (const float4*)(w1 + k * F_HID + j0);
            #pragma unroll
            for (int q = 0; q < 4; ++q) {
                float4 wv = wp[q];
                acc[4 * q + 0] += xv * wv.x;
                acc[4 * q + 1] += xv * wv.y;
                acc[4 * q + 2] += xv * wv.z;
                acc[4 * q + 3] += xv * wv.w;
            }
        }
        #pragma unroll
        for (int jj = 0; jj < 16; ++jj)
            h1s[m][j0 + jj] = fmaxf(acc[jj] + b1s[j0 + jj], 0.0f) * di;
    }
    __syncthreads();

    float o[16];
    #pragma unroll
    for (int jj = 0; jj < 16; ++jj) o[jj] = 0.0f;
    if (valid) {
        #pragma unroll 8
        for (int k = 0; k < F_HID; ++k) {
            float hv = h1s[m][k];
            const float4* wp = (const float4*)(w2 + k * F_HID + j0);
            #pragma unroll
            for (int q = 0; q < 4; ++q) {
                float4 wv = wp[q];
                o[4 * q + 0] += hv * wv.x;
                o[4 * q + 1] += hv * wv.y;
                o[4 * q + 2] += hv * wv.z;
                o[4 * q + 3] += hv * wv.w;
            }
        }
        union { float4 f4; __half2 h2[4]; } p0, p1;
        #pragma unroll
        for (int q = 0; q < 4; ++q) {
            p0.h2[q] = __float22half2_rn(make_float2(o[2 * q], o[2 * q + 1]));
            p1.h2[q] = __float22half2_rn(make_float2(o[8 + 2 * q], o[8 + 2 * q + 1]));
        }
        float4* dst = (float4*)(hw + (size_t)node * F_HID + j0);
        dst[0] = p0.f4;
        dst[1] = p1.f4;
    }
}

// Layer 2 aggregation + relu + segmented global_mean_pool (pure gather).
// 8-lane groups (16B float4/lane = 128B row in ONE load), 4-deep unroll.
__global__ void aggpool_kernel(const int* __restrict__ csr_src, const int* __restrict__ row_start,
                               const __half* __restrict__ hw, const float* __restrict__ dinv,
                               const int* __restrict__ batch1, const int* __restrict__ batch2,
                               const float* __restrict__ b2,
                               float* __restrict__ pooled, float* __restrict__ cnt,
                               int n, int G) {
    int n2 = 2 * n;
    int g8 = threadIdx.x >> 3, lane8 = threadIdx.x & 7;
    int gid = blockIdx.x * 32 + g8;
    int base = gid * NPG;
    if (base >= n2) return;
    int end_n = base + NPG;
    if (end_n > n2) end_n = n2;

    const float4 bias0 = *(const float4*)(b2 + lane8 * 8);
    const float4 bias1 = *(const float4*)(b2 + lane8 * 8 + 4);
    float4 pacc0 = make_float4(0.f, 0.f, 0.f, 0.f);
    float4 pacc1 = make_float4(0.f, 0.f, 0.f, 0.f);
    float count = 0.0f;
    int cur_b = (base < n) ? batch1[base] : (batch2[base - n] + G);

    for (int node = base; node < end_n; ++node) {
        int b = (node < n) ? batch1[node] : (batch2[node - n] + G);
        if (b != cur_b) {
            float* pp = pooled + (size_t)cur_b * F_HID + lane8 * 8;
            atomicAdd(pp + 0, pacc0.x); atomicAdd(pp + 1, pacc0.y);
            atomicAdd(pp + 2, pacc0.z); atomicAdd(pp + 3, pacc0.w);
            atomicAdd(pp + 4, pacc1.x); atomicAdd(pp + 5, pacc1.y);
            atomicAdd(pp + 6, pacc1.z); atomicAdd(pp + 7, pacc1.w);
            if (lane8 == 0) atomicAdd(&cnt[cur_b], count);
            pacc0 = make_float4(0.f, 0.f, 0.f, 0.f);
            pacc1 = make_float4(0.f, 0.f, 0.f, 0.f);
            count = 0.0f; cur_b = b;
        }
        int start = row_start[node], end = row_start[node + 1];
        float4 a0 = make_float4(0.f, 0.f, 0.f, 0.f);
        float4 a1 = make_float4(0.f, 0.f, 0.f, 0.f);
        int e = start;
        for (; e + 4 <= end; e += 4) {
            int i0 = csr_src[e + 0], i1 = csr_src[e + 1];
            int i2 = csr_src[e + 2], i3 = csr_src[e + 3];
            float4 r0 = *(const float4*)(hw + (size_t)i0 * F_HID + lane8 * 8);
            float4 r1 = *(const float4*)(hw + (size_t)i1 * F_HID + lane8 * 8);
            float4 r2 = *(const float4*)(hw + (size_t)i2 * F_HID + lane8 * 8);
            float4 r3 = *(const float4*)(hw + (size_t)i3 * F_HID + lane8 * 8);
            acc_row4(a0, a1, r0); acc_row4(a0, a1, r1);
            acc_row4(a0, a1, r2); acc_row4(a0, a1, r3);
        }
        for (; e < end; ++e) {
            float4 r0 = *(const float4*)(hw + (size_t)csr_src[e] * F_HID + lane8 * 8);
            acc_row4(a0, a1, r0);
        }
        float4 rs = *(const float4*)(hw + (size_t)node * F_HID + lane8 * 8);
        acc_row4(a0, a1, rs);
        float di = dinv[node];
        pacc0.x += fmaxf(bias0.x + di * a0.x, 0.0f);
        pacc0.y += fmaxf(bias0.y + di * a0.y, 0.0f);
        pacc0.z += fmaxf(bias0.z + di * a0.z, 0.0f);
        pacc0.w += fmaxf(bias0.w + di * a0.w, 0.0f);
        pacc1.x += fmaxf(bias1.x + di * a1.x, 0.0f);
        pacc1.y += fmaxf(bias1.y + di * a1.y, 0.0f);
        pacc1.z += fmaxf(bias1.z + di * a1.z, 0.0f);
        pacc1.w += fmaxf(bias1.w + di * a1.w, 0.0f);
        count += 1.0f;
    }
    float* pp = pooled + (size_t)cur_b * F_HID + lane8 * 8;
    atomicAdd(pp + 0, pacc0.x); atomicAdd(pp + 1, pacc0.y);
    atomicAdd(pp + 2, pacc0.z); atomicAdd(pp + 3, pacc0.w);
    atomicAdd(pp + 4, pacc1.x); atomicAdd(pp + 5, pacc1.y);
    atomicAdd(pp + 6, pacc1.z); atomicAdd(pp + 7, pacc1.w);
    if (lane8 == 0) atomicAdd(&cnt[cur_b], count);
}

// per graph: combined[128] -> relu(@Wf1 + bf1)[64] -> @Wf2 + bf2 -> out[2]
__global__ void head_kernel(const float* __restrict__ p1, const float* __restrict__ c1,
                            const float* __restrict__ p2, const float* __restrict__ c2,
                            const float* __restrict__ Wf1, const float* __restrict__ bf1,
                            const float* __restrict__ Wf2, const float* __restrict__ bf2,
                            float* __restrict__ out) {
    int g = blockIdx.x;
    int j = threadIdx.x;  // 64 threads, one wave
    __shared__ float comb[128];
    float inv1 = 1.0f / fmaxf(c1[g], 1.0f);
    float inv2 = 1.0f / fmaxf(c2[g], 1.0f);
    comb[j] = p1[g * 64 + j] * inv1;
    comb[64 + j] = p2[g * 64 + j] * inv2;
    __syncthreads();
    float acc = bf1[j];
    #pragma unroll
    for (int k = 0; k < 128; ++k) acc += comb[k] * Wf1[k * 64 + j];
    float h = fmaxf(acc, 0.0f);
    float o0 = h * Wf2[j * 2 + 0];
    float o1 = h * Wf2[j * 2 + 1];
    #pragma unroll
    for (int off = 32; off > 0; off >>= 1) {
        o0 += __shfl_down(o0, off);
        o1 += __shfl_down(o1, off);
    }
    if (j == 0) {
        out[g * 2 + 0] = o0 + bf2[0];
        out[g * 2 + 1] = o1 + bf2[1];
    }
}

extern "C" void kernel_launch(void* const* d_in, const int* in_sizes, int n_in,
                              void* d_out, int out_size, void* d_ws, size_t ws_size,
                              hipStream_t stream) {
    const float* x1     = (const float*)d_in[0];
    const int*   ei1    = (const int*)d_in[1];
    const int*   batch1 = (const int*)d_in[2];
    const float* x2     = (const float*)d_in[3];
    const int*   ei2    = (const int*)d_in[4];
    const int*   batch2 = (const int*)d_in[5];
    const float* W1     = (const float*)d_in[6];
    const float* b1     = (const float*)d_in[7];
    const float* W2     = (const float*)d_in[8];
    const float* b2     = (const float*)d_in[9];
    const float* Wf1    = (const float*)d_in[10];
    const float* bf1    = (const float*)d_in[11];
    const float* Wf2    = (const float*)d_in[12];
    const float* bf2    = (const float*)d_in[13];
    float* out = (float*)d_out;

    const int n = in_sizes[0] / F_IN;   // 100000
    const int E = in_sizes[1] / 2;      // 1600000
    const int G = out_size / 2;         // 256
    const int n2 = 2 * n;
    const int E2 = 2 * E;
    const int NBK = (n2 + BKN - 1) / BKN;         // coarse buckets (196)
    const int nblkA = (E2 + EPB - 1) / EPB;       // radix blocks (782)
    const int N_A = NBK * nblkA;                  // count-matrix entries
    const int nbA = (N_A + SCAN_CHUNK - 1) / SCAN_CHUNK;

    char* ws = (char*)d_ws;
    size_t off = 0;
    unsigned* count  = (unsigned*)(ws + off); off += (((size_t)N_A + 63) & ~63ull) * 4;
    unsigned* bsumA  = (unsigned*)(ws + off); off += (size_t)((nbA + 63) & ~63) * 4;
    int* row_start   = (int*)(ws + off);      off += (((size_t)n2 + 64) & ~63ull) * 4;
    int* csr_src     = (int*)(ws + off);      off += (size_t)E2 * 4;
    float* dinv      = (float*)(ws + off);    off += (size_t)n2 * 4;
    __half* xs       = (__half*)(ws + off);   off += (size_t)n2 * F_IN * 2;
    __half* hwbuf    = (__half*)(ws + off);   off += (size_t)n2 * F_HID * 2;
    float* pooled    = (float*)(ws + off);    off += 2 * (size_t)G * F_HID * 4;
    float* cnt       = (float*)(ws + off);    off += 2 * (size_t)G * 4;

    // pairs (E2 u32 = 12.8 MB) aliases hwbuf (25.6 MB): consumed by bucketB
    // before aggmlp writes hw. Stream-ordered -> safe.
    unsigned* pairs = (unsigned*)hwbuf;

    hipMemsetAsync(pooled, 0, (2 * (size_t)G * F_HID + 2 * (size_t)G) * sizeof(float), stream);

    histA_kernel<<<nblkA, 256, 0, stream>>>(ei1, ei2, E, n, count, nblkA, NBK, E2);
    scan1_kernel<<<nbA, 256, 0, stream>>>(count, bsumA, N_A);
    scan2_kernel<<<1, 64, 0, stream>>>(bsumA, nbA);
    scan3g_kernel<<<nbA, 256, 0, stream>>>(count, bsumA, N_A);
    passA2_kernel<<<nblkA, 256, 0, stream>>>(ei1, ei2, E, n, count, pairs, nblkA, NBK, E2);
    bucketB_kernel<<<NBK, 256, 0, stream>>>(pairs, count, x1, x2, row_start, dinv, xs,
                                            csr_src, n, n2, E2, nblkA, NBK);

    aggmlp_kernel<<<(n2 + 63) / 64, 256, 0, stream>>>(csr_src, row_start, xs, dinv,
                                                      W1, b1, W2, hwbuf, n2);

    const int groups = (n2 + NPG - 1) / NPG;
    aggpool_kernel<<<(groups + 31) / 32, 256, 0, stream>>>(
        csr_src, row_start, hwbuf, dinv, batch1, batch2, b2, pooled, cnt, n, G);

    head_kernel<<<G, 64, 0, stream>>>(pooled, cnt, pooled + (size_t)G * F_HID, cnt + G,
                                      Wf1, bf1, Wf2, bf2, out);
}

// Round 11
// 282.713 us; speedup vs baseline: 1.5403x; 1.5403x over previous
//
#include <hip/hip_runtime.h>
#include <hip/hip_fp16.h>

#define F_IN 16
#define F_HID 64
#define NPG 4            // nodes per 8-lane group in aggpool
#define NSLOT 8          // LDS segment slots per block (fallback: global atomics)
#define SCAN_CHUNK 1024
#define EPB 4096         // edges per radix block
#define BKN 1024         // nodes per coarse bucket (rel = 10 bits)

// Combined problem: both graphs concatenated. Node j in [0,2n): graph g=j/n.
// Edge e in [0,2E): graph g=e/E. Segment id = batch[g][..] + g*G.
// pairs word = (rel10 << 18) | src18   (2n = 200000 < 2^18)

// E and E2 are multiples of 4 (E = 1.6M), so int4 edge loads never straddle.
__device__ inline void load_edge4(const int* __restrict__ ei1, const int* __restrict__ ei2,
                                  int E, int n, int e4, int4& s4, int4& d4) {
    if (e4 < E) {
        s4 = *(const int4*)(ei1 + e4);
        d4 = *(const int4*)(ei1 + E + e4);
    } else {
        int eb = e4 - E;
        s4 = *(const int4*)(ei2 + eb);
        d4 = *(const int4*)(ei2 + E + eb);
        s4.x += n; s4.y += n; s4.z += n; s4.w += n;
        d4.x += n; d4.y += n; d4.z += n; d4.w += n;
    }
}

// ---- radix CSR build (no global atomics) ----------------------------------

// Pass A.1: per-block LDS histogram over coarse buckets -> count[bucket][blk]
__global__ void histA_kernel(const int* __restrict__ ei1, const int* __restrict__ ei2,
                             int E, int n, unsigned* __restrict__ count,
                             int nblkA, int NBK, int E2) {
    __shared__ unsigned hist[256];   // NBK <= 256
    for (int i = threadIdx.x; i < NBK; i += 256) hist[i] = 0;
    __syncthreads();
    int base = blockIdx.x * EPB;
    #pragma unroll
    for (int r = 0; r < EPB / 1024; ++r) {
        int e4 = base + r * 1024 + threadIdx.x * 4;
        if (e4 + 4 <= E2) {
            int4 s4, d4;
            load_edge4(ei1, ei2, E, n, e4, s4, d4);
            atomicAdd(&hist[d4.x >> 10], 1u);
            atomicAdd(&hist[d4.y >> 10], 1u);
            atomicAdd(&hist[d4.z >> 10], 1u);
            atomicAdd(&hist[d4.w >> 10], 1u);
        } else if (e4 < E2) {
            for (int e = e4; e < E2; ++e) {
                int d = (e < E) ? ei1[E + e] : (ei2[e] + n);
                atomicAdd(&hist[d >> 10], 1u);
            }
        }
    }
    __syncthreads();
    for (int i = threadIdx.x; i < NBK; i += 256)
        count[(size_t)i * nblkA + blockIdx.x] = hist[i];
}

__global__ void scan1_kernel(const unsigned* __restrict__ a, unsigned* __restrict__ bsum, int N) {
    __shared__ unsigned s[256];
    int base = blockIdx.x * SCAN_CHUNK;
    unsigned t = 0;
    for (int i = threadIdx.x; i < SCAN_CHUNK; i += 256) {
        int idx = base + i;
        if (idx < N) t += a[idx];
    }
    s[threadIdx.x] = t;
    __syncthreads();
    for (int o = 128; o > 0; o >>= 1) {
        if (threadIdx.x < o) s[threadIdx.x] += s[threadIdx.x + o];
        __syncthreads();
    }
    if (threadIdx.x == 0) bsum[blockIdx.x] = s[0];
}

__global__ void scan2_kernel(unsigned* __restrict__ bsum, int nb) {
    if (threadIdx.x == 0 && blockIdx.x == 0) {
        unsigned run = 0;
        for (int i = 0; i < nb; ++i) { unsigned v = bsum[i]; bsum[i] = run; run += v; }
    }
}

// generic in-place exclusive scan finalize
__global__ void scan3g_kernel(unsigned* __restrict__ a, const unsigned* __restrict__ bsum, int N) {
    __shared__ unsigned s[256];
    int tid = threadIdx.x;
    int base = blockIdx.x * SCAN_CHUNK;
    unsigned loc[4];
    unsigned t = 0;
    #pragma unroll
    for (int j = 0; j < 4; ++j) {
        int idx = base + tid * 4 + j;
        loc[j] = (idx < N) ? a[idx] : 0u;
        t += loc[j];
    }
    s[tid] = t;
    __syncthreads();
    for (int o = 1; o < 256; o <<= 1) {
        unsigned v = (tid >= o) ? s[tid - o] : 0u;
        __syncthreads();
        s[tid] += v;
        __syncthreads();
    }
    unsigned off = bsum[blockIdx.x] + s[tid] - t;
    #pragma unroll
    for (int j = 0; j < 4; ++j) {
        int idx = base + tid * 4 + j;
        if (idx < N) a[idx] = off;
        off += loc[j];
    }
}

// Pass A.2: place edges into pairs via LDS cursors (per-(block,bucket) runs
// are consecutive -> near-line-sized writes, zero global atomics).
__global__ void passA2_kernel(const int* __restrict__ ei1, const int* __restrict__ ei2,
                              int E, int n, const unsigned* __restrict__ cbase,
                              unsigned* __restrict__ pairs, int nblkA, int NBK, int E2) {
    __shared__ unsigned cur[256];
    for (int i = threadIdx.x; i < NBK; i += 256)
        cur[i] = cbase[(size_t)i * nblkA + blockIdx.x];
    __syncthreads();
    int base = blockIdx.x * EPB;
    #pragma unroll
    for (int r = 0; r < EPB / 1024; ++r) {
        int e4 = base + r * 1024 + threadIdx.x * 4;
        if (e4 + 4 <= E2) {
            int4 s4, d4;
            load_edge4(ei1, ei2, E, n, e4, s4, d4);
            unsigned p;
            p = atomicAdd(&cur[d4.x >> 10], 1u);
            pairs[p] = ((unsigned)(d4.x & 1023) << 18) | (unsigned)s4.x;
            p = atomicAdd(&cur[d4.y >> 10], 1u);
            pairs[p] = ((unsigned)(d4.y & 1023) << 18) | (unsigned)s4.y;
            p = atomicAdd(&cur[d4.z >> 10], 1u);
            pairs[p] = ((unsigned)(d4.z & 1023) << 18) | (unsigned)s4.z;
            p = atomicAdd(&cur[d4.w >> 10], 1u);
            pairs[p] = ((unsigned)(d4.w & 1023) << 18) | (unsigned)s4.w;
        } else if (e4 < E2) {
            for (int e = e4; e < E2; ++e) {
                int s = (e < E) ? ei1[e] : (ei2[e - E] + n);
                int d = (e < E) ? ei1[E + e] : (ei2[e] + n);
                unsigned p = atomicAdd(&cur[d >> 10], 1u);
                pairs[p] = ((unsigned)(d & 1023) << 18) | (unsigned)s;
            }
        }
    }
}

// Pass B: one block per bucket. From pairs: per-node degree (LDS), block scan
// -> row_start + dinv + prescaled fp16 xs; then place csr_src via LDS cursors.
__global__ void bucketB_kernel(const unsigned* __restrict__ pairs,
                               const unsigned* __restrict__ cbase,
                               const float* __restrict__ x1, const float* __restrict__ x2,
                               int* __restrict__ row_start, float* __restrict__ dinv,
                               __half* __restrict__ xs, int* __restrict__ csr_src,
                               int n, int n2, int E2, int nblkA, int NBK) {
    __shared__ unsigned cnt[BKN];
    __shared__ int cur[BKN];
    __shared__ unsigned s[256];
    int b = blockIdx.x;
    int nodebase = b * BKN;
    int nn = n2 - nodebase; if (nn > BKN) nn = BKN;
    unsigned begin = cbase[(size_t)b * nblkA];
    unsigned end = (b + 1 < NBK) ? cbase[(size_t)(b + 1) * nblkA] : (unsigned)E2;
    int t = threadIdx.x;

    for (int i = t; i < BKN; i += 256) cnt[i] = 0;
    __syncthreads();
    for (unsigned i = begin + t; i < end; i += 256)
        atomicAdd(&cnt[pairs[i] >> 18], 1u);
    __syncthreads();

    unsigned loc[4];
    unsigned tot = 0;
    #pragma unroll
    for (int j = 0; j < 4; ++j) { loc[j] = cnt[t * 4 + j]; tot += loc[j]; }
    s[t] = tot;
    __syncthreads();
    for (int o = 1; o < 256; o <<= 1) {
        unsigned v = (t >= o) ? s[t - o] : 0u;
        __syncthreads();
        s[t] += v;
        __syncthreads();
    }
    unsigned off = begin + s[t] - tot;
    #pragma unroll
    for (int j = 0; j < 4; ++j) {
        int i = t * 4 + j;
        if (i < nn) {
            int node = nodebase + i;
            row_start[node] = (int)off;
            cur[i] = (int)off;
            float di = rsqrtf((float)loc[j] + 1.0f);
            dinv[node] = di;
            const float* xr = (node < n) ? (x1 + (size_t)node * F_IN)
                                         : (x2 + (size_t)(node - n) * F_IN);
            const float4* xin = (const float4*)xr;
            union { float4 f4; __half2 h2[4]; } u;
            __half2* xo = (__half2*)(xs + (size_t)node * F_IN);
            #pragma unroll
            for (int c = 0; c < 2; ++c) {
                float4 v0 = xin[2 * c], v1 = xin[2 * c + 1];
                u.h2[0] = __float22half2_rn(make_float2(v0.x * di, v0.y * di));
                u.h2[1] = __float22half2_rn(make_float2(v0.z * di, v0.w * di));
                u.h2[2] = __float22half2_rn(make_float2(v1.x * di, v1.y * di));
                u.h2[3] = __float22half2_rn(make_float2(v1.z * di, v1.w * di));
                *(float4*)(xo + 4 * c) = u.f4;
            }
        }
        off += loc[j];
    }
    __syncthreads();
    for (unsigned i = begin + t; i < end; i += 256) {
        unsigned v = pairs[i];
        int pos = atomicAdd(&cur[v >> 18], 1);
        csr_src[pos] = (int)(v & 0x3FFFFu);
    }
    if (b == 0 && t == 0) row_start[n2] = E2;
}

// ---- fused gather+MLP / pool ----------------------------------------------

__device__ inline void acc_row2(float4& a, float2 r) {
    union { float2 f2; __half2 h2[2]; } u; u.f2 = r;
    float2 lo = __half22float2(u.h2[0]), hi = __half22float2(u.h2[1]);
    a.x += lo.x; a.y += lo.y; a.z += hi.x; a.w += hi.y;
}

__device__ inline void acc_row4(float4& a0, float4& a1, float4 r) {
    union { float4 f4; __half2 h2[4]; } u; u.f4 = r;
    float2 p0 = __half22float2(u.h2[0]), p1 = __half22float2(u.h2[1]);
    float2 p2 = __half22float2(u.h2[2]), p3 = __half22float2(u.h2[3]);
    a0.x += p0.x; a0.y += p0.y; a0.z += p1.x; a0.w += p1.y;
    a1.x += p2.x; a1.y += p2.y; a1.z += p3.x; a1.w += p3.y;
}

// Fused layer-1 gather + dense 2-layer MLP (W2 folded):
//   xagg = dinv*(sum_s xs[s] + xs[self])          (gather, 4 lanes/node)
//   hw   = (relu(xagg @ W1 + b1) * dinv) @ W2     (dense, LDS weights)
__global__ __launch_bounds__(256) void aggmlp_kernel(
        const int* __restrict__ csr_src, const int* __restrict__ row_start,
        const __half* __restrict__ xs, const float* __restrict__ dinv,
        const float* __restrict__ W1, const float* __restrict__ b1,
        const float* __restrict__ W2, __half* __restrict__ hw, int n2) {
    __shared__ __align__(16) float w1[F_IN * F_HID];
    __shared__ __align__(16) float w2[F_HID * F_HID];
    __shared__ float b1s[F_HID];
    __shared__ __align__(16) float xl[64][20];
    __shared__ __align__(16) float h1s[64][68];
    int t = threadIdx.x;
    for (int i = t; i < F_IN * F_HID; i += 256) w1[i] = W1[i];
    for (int i = t; i < F_HID * F_HID; i += 256) w2[i] = W2[i];
    if (t < F_HID) b1s[t] = b1[t];

    int base = blockIdx.x * 64;
    int m = t >> 2, jg = t & 3, j0 = jg * 16;
    int node = base + m;
    bool valid = node < n2;
    float di = 0.0f;

    if (valid) {
        int start = row_start[node], end = row_start[node + 1];
        float4 acc = make_float4(0.f, 0.f, 0.f, 0.f);
        int e = start;
        for (; e + 4 <= end; e += 4) {
            int i0 = csr_src[e + 0], i1 = csr_src[e + 1];
            int i2 = csr_src[e + 2], i3 = csr_src[e + 3];
            float2 r0 = *(const float2*)(xs + (size_t)i0 * F_IN + jg * 4);
            float2 r1 = *(const float2*)(xs + (size_t)i1 * F_IN + jg * 4);
            float2 r2 = *(const float2*)(xs + (size_t)i2 * F_IN + jg * 4);
            float2 r3 = *(const float2*)(xs + (size_t)i3 * F_IN + jg * 4);
            acc_row2(acc, r0); acc_row2(acc, r1); acc_row2(acc, r2); acc_row2(acc, r3);
        }
        for (; e < end; ++e) {
            float2 r0 = *(const float2*)(xs + (size_t)csr_src[e] * F_IN + jg * 4);
            acc_row2(acc, r0);
        }
        float2 rs = *(const float2*)(xs + (size_t)node * F_IN + jg * 4);
        acc_row2(acc, rs);
        di = dinv[node];
        *(float4*)&xl[m][jg * 4] =
            make_float4(acc.x * di, acc.y * di, acc.z * di, acc.w * di);
    }
    __syncthreads();

    float acc[16];
    #pragma unroll
    for (int jj = 0; jj < 16; ++jj) acc[jj] = 0.0f;
    if (valid) {
        #pragma unroll
        for (int k = 0; k < F_IN; ++k) {
            float xv = xl[m][k];
            const float4* wp = (const float4*)(w1 + k * F_HID + j0);
            #pragma unroll
            for (int q = 0; q < 4; ++q) {
                float4 wv = wp[q];
                acc[4 * q + 0] += xv * wv.x;
                acc[4 * q + 1] += xv * wv.y;
                acc[4 * q + 2] += xv * wv.z;
                acc[4 * q + 3] += xv * wv.w;
            }
        }
        #pragma unroll
        for (int jj = 0; jj < 16; ++jj)
            h1s[m][j0 + jj] = fmaxf(acc[jj] + b1s[j0 + jj], 0.0f) * di;
    }
    __syncthreads();

    float o[16];
    #pragma unroll
    for (int jj = 0; jj < 16; ++jj) o[jj] = 0.0f;
    if (valid) {
        #pragma unroll 8
        for (int k = 0; k < F_HID; ++k) {
            float hv = h1s[m][k];
            const float4* wp = (const float4*)(w2 + k * F_HID + j0);
            #pragma unroll
            for (int q = 0; q < 4; ++q) {
                float4 wv = wp[q];
                o[4 * q + 0] += hv * wv.x;
                o[4 * q + 1] += hv * wv.y;
                o[4 * q + 2] += hv * wv.z;
                o[4 * q + 3] += hv * wv.w;
            }
        }
        union { float4 f4; __half2 h2[4]; } p0, p1;
        #pragma unroll
        for (int q = 0; q < 4; ++q) {
            p0.h2[q] = __float22half2_rn(make_float2(o[2 * q], o[2 * q + 1]));
            p1.h2[q] = __float22half2_rn(make_float2(o[8 + 2 * q], o[8 + 2 * q + 1]));
        }
        float4* dst = (float4*)(hw + (size_t)node * F_HID + j0);
        dst[0] = p0.f4;
        dst[1] = p1.f4;
    }
}

// Layer 2 aggregation + relu + segmented global_mean_pool (pure gather).
// 8-lane groups, float4 loads (one load per 128B row), NPG=4 for parallelism.
// Segment flushes go to block-level LDS accumulators (slot = seg - block_seg0),
// drained once per block: global atomics drop ~16x vs per-group flushing.
__global__ __launch_bounds__(256) void aggpool_kernel(
        const int* __restrict__ csr_src, const int* __restrict__ row_start,
        const __half* __restrict__ hw, const float* __restrict__ dinv,
        const int* __restrict__ batch1, const int* __restrict__ batch2,
        const float* __restrict__ b2,
        float* __restrict__ pooled, float* __restrict__ cnt,
        int n, int G) {
    __shared__ float segacc[NSLOT][F_HID];
    __shared__ float segcnt[NSLOT];
    __shared__ int bb0;
    int n2 = 2 * n;
    int t = threadIdx.x;
    int block_base = blockIdx.x * (32 * NPG);   // 32 groups x NPG nodes

    for (int i = t; i < NSLOT * F_HID; i += 256) (&segacc[0][0])[i] = 0.0f;
    if (t < NSLOT) segcnt[t] = 0.0f;
    if (t == 0)
        bb0 = (block_base < n) ? batch1[block_base] : (batch2[block_base - n] + G);
    __syncthreads();
    int b0 = bb0;

    int g8 = t >> 3, lane8 = t & 7;
    int base = block_base + g8 * NPG;
    if (base < n2) {
        int end_n = base + NPG; if (end_n > n2) end_n = n2;
        const float4 bias0 = *(const float4*)(b2 + lane8 * 8);
        const float4 bias1 = *(const float4*)(b2 + lane8 * 8 + 4);
        float4 pacc0 = make_float4(0.f, 0.f, 0.f, 0.f);
        float4 pacc1 = make_float4(0.f, 0.f, 0.f, 0.f);
        float count = 0.0f;
        int cur_b = (base < n) ? batch1[base] : (batch2[base - n] + G);

        for (int node = base; node < end_n; ++node) {
            int b = (node < n) ? batch1[node] : (batch2[node - n] + G);
            if (b != cur_b) {
                int slot = cur_b - b0;
                if (slot < NSLOT) {
                    float* sp = &segacc[slot][lane8 * 8];
                    atomicAdd(sp + 0, pacc0.x); atomicAdd(sp + 1, pacc0.y);
                    atomicAdd(sp + 2, pacc0.z); atomicAdd(sp + 3, pacc0.w);
                    atomicAdd(sp + 4, pacc1.x); atomicAdd(sp + 5, pacc1.y);
                    atomicAdd(sp + 6, pacc1.z); atomicAdd(sp + 7, pacc1.w);
                    if (lane8 == 0) atomicAdd(&segcnt[slot], count);
                } else {
                    float* pp = pooled + (size_t)cur_b * F_HID + lane8 * 8;
                    atomicAdd(pp + 0, pacc0.x); atomicAdd(pp + 1, pacc0.y);
                    atomicAdd(pp + 2, pacc0.z); atomicAdd(pp + 3, pacc0.w);
                    atomicAdd(pp + 4, pacc1.x); atomicAdd(pp + 5, pacc1.y);
                    atomicAdd(pp + 6, pacc1.z); atomicAdd(pp + 7, pacc1.w);
                    if (lane8 == 0) atomicAdd(&cnt[cur_b], count);
                }
                pacc0 = make_float4(0.f, 0.f, 0.f, 0.f);
                pacc1 = make_float4(0.f, 0.f, 0.f, 0.f);
                count = 0.0f; cur_b = b;
            }
            int start = row_start[node], end = row_start[node + 1];
            float4 a0 = make_float4(0.f, 0.f, 0.f, 0.f);
            float4 a1 = make_float4(0.f, 0.f, 0.f, 0.f);
            int e = start;
            for (; e + 4 <= end; e += 4) {
                int i0 = csr_src[e + 0], i1 = csr_src[e + 1];
                int i2 = csr_src[e + 2], i3 = csr_src[e + 3];
                float4 r0 = *(const float4*)(hw + (size_t)i0 * F_HID + lane8 * 8);
                float4 r1 = *(const float4*)(hw + (size_t)i1 * F_HID + lane8 * 8);
                float4 r2 = *(const float4*)(hw + (size_t)i2 * F_HID + lane8 * 8);
                float4 r3 = *(const float4*)(hw + (size_t)i3 * F_HID + lane8 * 8);
                acc_row4(a0, a1, r0); acc_row4(a0, a1, r1);
                acc_row4(a0, a1, r2); acc_row4(a0, a1, r3);
            }
            for (; e < end; ++e) {
                float4 r0 = *(const float4*)(hw + (size_t)csr_src[e] * F_HID + lane8 * 8);
                acc_row4(a0, a1, r0);
            }
            float4 rs = *(const float4*)(hw + (size_t)node * F_HID + lane8 * 8);
            acc_row4(a0, a1, rs);
            float di = dinv[node];
            pacc0.x += fmaxf(bias0.x + di * a0.x, 0.0f);
            pacc0.y += fmaxf(bias0.y + di * a0.y, 0.0f);
            pacc0.z += fmaxf(bias0.z + di * a0.z, 0.0f);
            pacc0.w += fmaxf(bias0.w + di * a0.w, 0.0f);
            pacc1.x += fmaxf(bias1.x + di * a1.x, 0.0f);
            pacc1.y += fmaxf(bias1.y + di * a1.y, 0.0f);
            pacc1.z += fmaxf(bias1.z + di * a1.z, 0.0f);
            pacc1.w += fmaxf(bias1.w + di * a1.w, 0.0f);
            count += 1.0f;
        }
        // final flush
        {
            int slot = cur_b - b0;
            if (slot < NSLOT) {
                float* sp = &segacc[slot][lane8 * 8];
                atomicAdd(sp + 0, pacc0.x); atomicAdd(sp + 1, pacc0.y);
                atomicAdd(sp + 2, pacc0.z); atomicAdd(sp + 3, pacc0.w);
                atomicAdd(sp + 4, pacc1.x); atomicAdd(sp + 5, pacc1.y);
                atomicAdd(sp + 6, pacc1.z); atomicAdd(sp + 7, pacc1.w);
                if (lane8 == 0) atomicAdd(&segcnt[slot], count);
            } else {
                float* pp = pooled + (size_t)cur_b * F_HID + lane8 * 8;
                atomicAdd(pp + 0, pacc0.x); atomicAdd(pp + 1, pacc0.y);
                atomicAdd(pp + 2, pacc0.z); atomicAdd(pp + 3, pacc0.w);
                atomicAdd(pp + 4, pacc1.x); atomicAdd(pp + 5, pacc1.y);
                atomicAdd(pp + 6, pacc1.z); atomicAdd(pp + 7, pacc1.w);
                if (lane8 == 0) atomicAdd(&cnt[cur_b], count);
            }
        }
    }
    __syncthreads();
    // drain LDS slots: 4 slots per pass (64 lanes each), 2 passes
    int s0 = t >> 6, l64 = t & 63;
    #pragma unroll
    for (int ss = s0; ss < NSLOT; ss += 4) {
        int seg = b0 + ss;
        if (seg < 2 * G) {
            float v = segacc[ss][l64];
            if (v != 0.0f) atomicAdd(&pooled[(size_t)seg * F_HID + l64], v);
            if (l64 == 0) {
                float c = segcnt[ss];
                if (c != 0.0f) atomicAdd(&cnt[seg], c);
            }
        }
    }
}

// per graph: combined[128] -> relu(@Wf1 + bf1)[64] -> @Wf2 + bf2 -> out[2]
__global__ void head_kernel(const float* __restrict__ p1, const float* __restrict__ c1,
                            const float* __restrict__ p2, const float* __restrict__ c2,
                            const float* __restrict__ Wf1, const float* __restrict__ bf1,
                            const float* __restrict__ Wf2, const float* __restrict__ bf2,
                            float* __restrict__ out) {
    int g = blockIdx.x;
    int j = threadIdx.x;  // 64 threads, one wave
    __shared__ float comb[128];
    float inv1 = 1.0f / fmaxf(c1[g], 1.0f);
    float inv2 = 1.0f / fmaxf(c2[g], 1.0f);
    comb[j] = p1[g * 64 + j] * inv1;
    comb[64 + j] = p2[g * 64 + j] * inv2;
    __syncthreads();
    float acc = bf1[j];
    #pragma unroll
    for (int k = 0; k < 128; ++k) acc += comb[k] * Wf1[k * 64 + j];
    float h = fmaxf(acc, 0.0f);
    float o0 = h * Wf2[j * 2 + 0];
    float o1 = h * Wf2[j * 2 + 1];
    #pragma unroll
    for (int off = 32; off > 0; off >>= 1) {
        o0 += __shfl_down(o0, off);
        o1 += __shfl_down(o1, off);
    }
    if (j == 0) {
        out[g * 2 + 0] = o0 + bf2[0];
        out[g * 2 + 1] = o1 + bf2[1];
    }
}

extern "C" void kernel_launch(void* const* d_in, const int* in_sizes, int n_in,
                              void* d_out, int out_size, void* d_ws, size_t ws_size,
                              hipStream_t stream) {
    const float* x1     = (const float*)d_in[0];
    const int*   ei1    = (const int*)d_in[1];
    const int*   batch1 = (const int*)d_in[2];
    const float* x2     = (const float*)d_in[3];
    const int*   ei2    = (const int*)d_in[4];
    const int*   batch2 = (const int*)d_in[5];
    const float* W1     = (const float*)d_in[6];
    const float* b1     = (const float*)d_in[7];
    const float* W2     = (const float*)d_in[8];
    const float* b2     = (const float*)d_in[9];
    const float* Wf1    = (const float*)d_in[10];
    const float* bf1    = (const float*)d_in[11];
    const float* Wf2    = (const float*)d_in[12];
    const float* bf2    = (const float*)d_in[13];
    float* out = (float*)d_out;

    const int n = in_sizes[0] / F_IN;   // 100000
    const int E = in_sizes[1] / 2;      // 1600000
    const int G = out_size / 2;         // 256
    const int n2 = 2 * n;
    const int E2 = 2 * E;
    const int NBK = (n2 + BKN - 1) / BKN;         // coarse buckets (196)
    const int nblkA = (E2 + EPB - 1) / EPB;       // radix blocks (782)
    const int N_A = NBK * nblkA;                  // count-matrix entries
    const int nbA = (N_A + SCAN_CHUNK - 1) / SCAN_CHUNK;

    char* ws = (char*)d_ws;
    size_t off = 0;
    unsigned* count  = (unsigned*)(ws + off); off += (((size_t)N_A + 63) & ~63ull) * 4;
    unsigned* bsumA  = (unsigned*)(ws + off); off += (size_t)((nbA + 63) & ~63) * 4;
    int* row_start   = (int*)(ws + off);      off += (((size_t)n2 + 64) & ~63ull) * 4;
    int* csr_src     = (int*)(ws + off);      off += (size_t)E2 * 4;
    float* dinv      = (float*)(ws + off);    off += (size_t)n2 * 4;
    __half* xs       = (__half*)(ws + off);   off += (size_t)n2 * F_IN * 2;
    __half* hwbuf    = (__half*)(ws + off);   off += (size_t)n2 * F_HID * 2;
    float* pooled    = (float*)(ws + off);    off += 2 * (size_t)G * F_HID * 4;
    float* cnt       = (float*)(ws + off);    off += 2 * (size_t)G * 4;

    // pairs (E2 u32 = 12.8 MB) aliases hwbuf (25.6 MB): consumed by bucketB
    // before aggmlp writes hw. Stream-ordered -> safe.
    unsigned* pairs = (unsigned*)hwbuf;

    hipMemsetAsync(pooled, 0, (2 * (size_t)G * F_HID + 2 * (size_t)G) * sizeof(float), stream);

    histA_kernel<<<nblkA, 256, 0, stream>>>(ei1, ei2, E, n, count, nblkA, NBK, E2);
    scan1_kernel<<<nbA, 256, 0, stream>>>(count, bsumA, N_A);
    scan2_kernel<<<1, 64, 0, stream>>>(bsumA, nbA);
    scan3g_kernel<<<nbA, 256, 0, stream>>>(count, bsumA, N_A);
    passA2_kernel<<<nblkA, 256, 0, stream>>>(ei1, ei2, E, n, count, pairs, nblkA, NBK, E2);
    bucketB_kernel<<<NBK, 256, 0, stream>>>(pairs, count, x1, x2, row_start, dinv, xs,
                                            csr_src, n, n2, E2, nblkA, NBK);

    aggmlp_kernel<<<(n2 + 63) / 64, 256, 0, stream>>>(csr_src, row_start, xs, dinv,
                                                      W1, b1, W2, hwbuf, n2);

    const int groups = (n2 + NPG - 1) / NPG;
    aggpool_kernel<<<(groups + 31) / 32, 256, 0, stream>>>(
        csr_src, row_start, hwbuf, dinv, batch1, batch2, b2, pooled, cnt, n, G);

    head_kernel<<<G, 64, 0, stream>>>(pooled, cnt, pooled + (size_t)G * F_HID, cnt + G,
                                      Wf1, bf1, Wf2, bf2, out);
}

// Round 12
// 276.390 us; speedup vs baseline: 1.5755x; 1.0229x over previous
//
#include <hip/hip_runtime.h>
#include <hip/hip_fp16.h>

#define F_IN 16
#define F_HID 64
#define NPG 2            // nodes per 8-lane group in aggpool
#define NSLOT 8          // LDS segment slots per block (fallback: global atomics)
#define SCAN_CHUNK 1024
#define EPB 4096         // edges per radix block
#define BKN 1024         // nodes per coarse bucket (rel = 10 bits)

// Combined problem: both graphs concatenated. Node j in [0,2n): graph g=j/n.
// Edge e in [0,2E): graph g=e/E. Segment id = batch[g][..] + g*G.
// pairs word = (rel10 << 18) | src18   (2n = 200000 < 2^18)

// E and E2 are multiples of 4 (E = 1.6M), so int4 edge loads never straddle.
__device__ inline void load_edge4(const int* __restrict__ ei1, const int* __restrict__ ei2,
                                  int E, int n, int e4, int4& s4, int4& d4) {
    if (e4 < E) {
        s4 = *(const int4*)(ei1 + e4);
        d4 = *(const int4*)(ei1 + E + e4);
    } else {
        int eb = e4 - E;
        s4 = *(const int4*)(ei2 + eb);
        d4 = *(const int4*)(ei2 + E + eb);
        s4.x += n; s4.y += n; s4.z += n; s4.w += n;
        d4.x += n; d4.y += n; d4.z += n; d4.w += n;
    }
}

// ---- radix CSR build (no global atomics) ----------------------------------

// Pass A.1: per-block LDS histogram over coarse buckets -> count[bucket][blk]
__global__ void histA_kernel(const int* __restrict__ ei1, const int* __restrict__ ei2,
                             int E, int n, unsigned* __restrict__ count,
                             int nblkA, int NBK, int E2) {
    __shared__ unsigned hist[256];   // NBK <= 256
    for (int i = threadIdx.x; i < NBK; i += 256) hist[i] = 0;
    __syncthreads();
    int base = blockIdx.x * EPB;
    #pragma unroll
    for (int r = 0; r < EPB / 1024; ++r) {
        int e4 = base + r * 1024 + threadIdx.x * 4;
        if (e4 + 4 <= E2) {
            int4 s4, d4;
            load_edge4(ei1, ei2, E, n, e4, s4, d4);
            atomicAdd(&hist[d4.x >> 10], 1u);
            atomicAdd(&hist[d4.y >> 10], 1u);
            atomicAdd(&hist[d4.z >> 10], 1u);
            atomicAdd(&hist[d4.w >> 10], 1u);
        } else if (e4 < E2) {
            for (int e = e4; e < E2; ++e) {
                int d = (e < E) ? ei1[E + e] : (ei2[e] + n);
                atomicAdd(&hist[d >> 10], 1u);
            }
        }
    }
    __syncthreads();
    for (int i = threadIdx.x; i < NBK; i += 256)
        count[(size_t)i * nblkA + blockIdx.x] = hist[i];
}

__global__ void scan1_kernel(const unsigned* __restrict__ a, unsigned* __restrict__ bsum, int N) {
    __shared__ unsigned s[256];
    int base = blockIdx.x * SCAN_CHUNK;
    unsigned t = 0;
    for (int i = threadIdx.x; i < SCAN_CHUNK; i += 256) {
        int idx = base + i;
        if (idx < N) t += a[idx];
    }
    s[threadIdx.x] = t;
    __syncthreads();
    for (int o = 128; o > 0; o >>= 1) {
        if (threadIdx.x < o) s[threadIdx.x] += s[threadIdx.x + o];
        __syncthreads();
    }
    if (threadIdx.x == 0) bsum[blockIdx.x] = s[0];
}

__global__ void scan2_kernel(unsigned* __restrict__ bsum, int nb) {
    if (threadIdx.x == 0 && blockIdx.x == 0) {
        unsigned run = 0;
        for (int i = 0; i < nb; ++i) { unsigned v = bsum[i]; bsum[i] = run; run += v; }
    }
}

// generic in-place exclusive scan finalize
__global__ void scan3g_kernel(unsigned* __restrict__ a, const unsigned* __restrict__ bsum, int N) {
    __shared__ unsigned s[256];
    int tid = threadIdx.x;
    int base = blockIdx.x * SCAN_CHUNK;
    unsigned loc[4];
    unsigned t = 0;
    #pragma unroll
    for (int j = 0; j < 4; ++j) {
        int idx = base + tid * 4 + j;
        loc[j] = (idx < N) ? a[idx] : 0u;
        t += loc[j];
    }
    s[tid] = t;
    __syncthreads();
    for (int o = 1; o < 256; o <<= 1) {
        unsigned v = (tid >= o) ? s[tid - o] : 0u;
        __syncthreads();
        s[tid] += v;
        __syncthreads();
    }
    unsigned off = bsum[blockIdx.x] + s[tid] - t;
    #pragma unroll
    for (int j = 0; j < 4; ++j) {
        int idx = base + tid * 4 + j;
        if (idx < N) a[idx] = off;
        off += loc[j];
    }
}

// Pass A.2: place edges into pairs via LDS cursors (per-(block,bucket) runs
// are consecutive -> near-line-sized writes, zero global atomics).
__global__ void passA2_kernel(const int* __restrict__ ei1, const int* __restrict__ ei2,
                              int E, int n, const unsigned* __restrict__ cbase,
                              unsigned* __restrict__ pairs, int nblkA, int NBK, int E2) {
    __shared__ unsigned cur[256];
    for (int i = threadIdx.x; i < NBK; i += 256)
        cur[i] = cbase[(size_t)i * nblkA + blockIdx.x];
    __syncthreads();
    int base = blockIdx.x * EPB;
    #pragma unroll
    for (int r = 0; r < EPB / 1024; ++r) {
        int e4 = base + r * 1024 + threadIdx.x * 4;
        if (e4 + 4 <= E2) {
            int4 s4, d4;
            load_edge4(ei1, ei2, E, n, e4, s4, d4);
            unsigned p;
            p = atomicAdd(&cur[d4.x >> 10], 1u);
            pairs[p] = ((unsigned)(d4.x & 1023) << 18) | (unsigned)s4.x;
            p = atomicAdd(&cur[d4.y >> 10], 1u);
            pairs[p] = ((unsigned)(d4.y & 1023) << 18) | (unsigned)s4.y;
            p = atomicAdd(&cur[d4.z >> 10], 1u);
            pairs[p] = ((unsigned)(d4.z & 1023) << 18) | (unsigned)s4.z;
            p = atomicAdd(&cur[d4.w >> 10], 1u);
            pairs[p] = ((unsigned)(d4.w & 1023) << 18) | (unsigned)s4.w;
        } else if (e4 < E2) {
            for (int e = e4; e < E2; ++e) {
                int s = (e < E) ? ei1[e] : (ei2[e - E] + n);
                int d = (e < E) ? ei1[E + e] : (ei2[e] + n);
                unsigned p = atomicAdd(&cur[d >> 10], 1u);
                pairs[p] = ((unsigned)(d & 1023) << 18) | (unsigned)s;
            }
        }
    }
}

// Pass B: one block per bucket. From pairs: per-node degree (LDS), block scan
// -> row_start + dinv + prescaled fp16 xs; then place csr_src via LDS cursors.
__global__ void bucketB_kernel(const unsigned* __restrict__ pairs,
                               const unsigned* __restrict__ cbase,
                               const float* __restrict__ x1, const float* __restrict__ x2,
                               int* __restrict__ row_start, float* __restrict__ dinv,
                               __half* __restrict__ xs, int* __restrict__ csr_src,
                               int n, int n2, int E2, int nblkA, int NBK) {
    __shared__ unsigned cnt[BKN];
    __shared__ int cur[BKN];
    __shared__ unsigned s[256];
    int b = blockIdx.x;
    int nodebase = b * BKN;
    int nn = n2 - nodebase; if (nn > BKN) nn = BKN;
    unsigned begin = cbase[(size_t)b * nblkA];
    unsigned end = (b + 1 < NBK) ? cbase[(size_t)(b + 1) * nblkA] : (unsigned)E2;
    int t = threadIdx.x;

    for (int i = t; i < BKN; i += 256) cnt[i] = 0;
    __syncthreads();
    for (unsigned i = begin + t; i < end; i += 256)
        atomicAdd(&cnt[pairs[i] >> 18], 1u);
    __syncthreads();

    unsigned loc[4];
    unsigned tot = 0;
    #pragma unroll
    for (int j = 0; j < 4; ++j) { loc[j] = cnt[t * 4 + j]; tot += loc[j]; }
    s[t] = tot;
    __syncthreads();
    for (int o = 1; o < 256; o <<= 1) {
        unsigned v = (t >= o) ? s[t - o] : 0u;
        __syncthreads();
        s[t] += v;
        __syncthreads();
    }
    unsigned off = begin + s[t] - tot;
    #pragma unroll
    for (int j = 0; j < 4; ++j) {
        int i = t * 4 + j;
        if (i < nn) {
            int node = nodebase + i;
            row_start[node] = (int)off;
            cur[i] = (int)off;
            float di = rsqrtf((float)loc[j] + 1.0f);
            dinv[node] = di;
            const float* xr = (node < n) ? (x1 + (size_t)node * F_IN)
                                         : (x2 + (size_t)(node - n) * F_IN);
            const float4* xin = (const float4*)xr;
            union { float4 f4; __half2 h2[4]; } u;
            __half2* xo = (__half2*)(xs + (size_t)node * F_IN);
            #pragma unroll
            for (int c = 0; c < 2; ++c) {
                float4 v0 = xin[2 * c], v1 = xin[2 * c + 1];
                u.h2[0] = __float22half2_rn(make_float2(v0.x * di, v0.y * di));
                u.h2[1] = __float22half2_rn(make_float2(v0.z * di, v0.w * di));
                u.h2[2] = __float22half2_rn(make_float2(v1.x * di, v1.y * di));
                u.h2[3] = __float22half2_rn(make_float2(v1.z * di, v1.w * di));
                *(float4*)(xo + 4 * c) = u.f4;
            }
        }
        off += loc[j];
    }
    __syncthreads();
    for (unsigned i = begin + t; i < end; i += 256) {
        unsigned v = pairs[i];
        int pos = atomicAdd(&cur[v >> 18], 1);
        csr_src[pos] = (int)(v & 0x3FFFFu);
    }
    if (b == 0 && t == 0) row_start[n2] = E2;
}

// ---- fused gather+MLP / pool ----------------------------------------------

__device__ inline void acc_row2(float4& a, float2 r) {
    union { float2 f2; __half2 h2[2]; } u; u.f2 = r;
    float2 lo = __half22float2(u.h2[0]), hi = __half22float2(u.h2[1]);
    a.x += lo.x; a.y += lo.y; a.z += hi.x; a.w += hi.y;
}

__device__ inline void acc_row4(float4& a0, float4& a1, float4 r) {
    union { float4 f4; __half2 h2[4]; } u; u.f4 = r;
    float2 p0 = __half22float2(u.h2[0]), p1 = __half22float2(u.h2[1]);
    float2 p2 = __half22float2(u.h2[2]), p3 = __half22float2(u.h2[3]);
    a0.x += p0.x; a0.y += p0.y; a0.z += p1.x; a0.w += p1.y;
    a1.x += p2.x; a1.y += p2.y; a1.z += p3.x; a1.w += p3.y;
}

// Fused layer-1 gather + dense 2-layer MLP (W2 folded):
//   xagg = dinv*(sum_s xs[s] + xs[self])          (gather, 4 lanes/node, 8-deep)
//   hw   = (relu(xagg @ W1 + b1) * dinv) @ W2     (dense, LDS weights)
__global__ __launch_bounds__(256) void aggmlp_kernel(
        const int* __restrict__ csr_src, const int* __restrict__ row_start,
        const __half* __restrict__ xs, const float* __restrict__ dinv,
        const float* __restrict__ W1, const float* __restrict__ b1,
        const float* __restrict__ W2, __half* __restrict__ hw, int n2) {
    __shared__ __align__(16) float w1[F_IN * F_HID];
    __shared__ __align__(16) float w2[F_HID * F_HID];
    __shared__ float b1s[F_HID];
    __shared__ __align__(16) float xl[64][20];
    __shared__ __align__(16) float h1s[64][68];
    int t = threadIdx.x;
    for (int i = t; i < F_IN * F_HID; i += 256) w1[i] = W1[i];
    for (int i = t; i < F_HID * F_HID; i += 256) w2[i] = W2[i];
    if (t < F_HID) b1s[t] = b1[t];

    int base = blockIdx.x * 64;
    int m = t >> 2, jg = t & 3, j0 = jg * 16;
    int node = base + m;
    bool valid = node < n2;
    float di = 0.0f;

    if (valid) {
        int start = row_start[node], end = row_start[node + 1];
        float4 a0 = make_float4(0.f, 0.f, 0.f, 0.f);
        float4 a1 = make_float4(0.f, 0.f, 0.f, 0.f);
        int e = start;
        for (; e + 8 <= end; e += 8) {
            int i0 = csr_src[e + 0], i1 = csr_src[e + 1];
            int i2 = csr_src[e + 2], i3 = csr_src[e + 3];
            int i4 = csr_src[e + 4], i5 = csr_src[e + 5];
            int i6 = csr_src[e + 6], i7 = csr_src[e + 7];
            float2 r0 = *(const float2*)(xs + (size_t)i0 * F_IN + jg * 4);
            float2 r1 = *(const float2*)(xs + (size_t)i1 * F_IN + jg * 4);
            float2 r2 = *(const float2*)(xs + (size_t)i2 * F_IN + jg * 4);
            float2 r3 = *(const float2*)(xs + (size_t)i3 * F_IN + jg * 4);
            float2 r4 = *(const float2*)(xs + (size_t)i4 * F_IN + jg * 4);
            float2 r5 = *(const float2*)(xs + (size_t)i5 * F_IN + jg * 4);
            float2 r6 = *(const float2*)(xs + (size_t)i6 * F_IN + jg * 4);
            float2 r7 = *(const float2*)(xs + (size_t)i7 * F_IN + jg * 4);
            acc_row2(a0, r0); acc_row2(a0, r1); acc_row2(a0, r2); acc_row2(a0, r3);
            acc_row2(a1, r4); acc_row2(a1, r5); acc_row2(a1, r6); acc_row2(a1, r7);
        }
        for (; e + 4 <= end; e += 4) {
            int i0 = csr_src[e + 0], i1 = csr_src[e + 1];
            int i2 = csr_src[e + 2], i3 = csr_src[e + 3];
            float2 r0 = *(const float2*)(xs + (size_t)i0 * F_IN + jg * 4);
            float2 r1 = *(const float2*)(xs + (size_t)i1 * F_IN + jg * 4);
            float2 r2 = *(const float2*)(xs + (size_t)i2 * F_IN + jg * 4);
            float2 r3 = *(const float2*)(xs + (size_t)i3 * F_IN + jg * 4);
            acc_row2(a0, r0); acc_row2(a0, r1); acc_row2(a0, r2); acc_row2(a0, r3);
        }
        for (; e < end; ++e) {
            float2 r0 = *(const float2*)(xs + (size_t)csr_src[e] * F_IN + jg * 4);
            acc_row2(a0, r0);
        }
        float2 rs = *(const float2*)(xs + (size_t)node * F_IN + jg * 4);
        acc_row2(a0, rs);
        a0.x += a1.x; a0.y += a1.y; a0.z += a1.z; a0.w += a1.w;
        di = dinv[node];
        *(float4*)&xl[m][jg * 4] =
            make_float4(a0.x * di, a0.y * di, a0.z * di, a0.w * di);
    }
    __syncthreads();

    float acc[16];
    #pragma unroll
    for (int jj = 0; jj < 16; ++jj) acc[jj] = 0.0f;
    if (valid) {
        #pragma unroll
        for (int k = 0; k < F_IN; ++k) {
            float xv = xl[m][k];
            const float4* wp = (const float4*)(w1 + k * F_HID + j0);
            #pragma unroll
            for (int q = 0; q < 4; ++q) {
                float4 wv = wp[q];
                acc[4 * q + 0] += xv * wv.x;
                acc[4 * q + 1] += xv * wv.y;
                acc[4 * q + 2] += xv * wv.z;
                acc[4 * q + 3] += xv * wv.w;
            }
        }
        #pragma unroll
        for (int jj = 0; jj < 16; ++jj)
            h1s[m][j0 + jj] = fmaxf(acc[jj] + b1s[j0 + jj], 0.0f) * di;
    }
    __syncthreads();

    float o[16];
    #pragma unroll
    for (int jj = 0; jj < 16; ++jj) o[jj] = 0.0f;
    if (valid) {
        #pragma unroll 8
        for (int k = 0; k < F_HID; ++k) {
            float hv = h1s[m][k];
            const float4* wp = (const float4*)(w2 + k * F_HID + j0);
            #pragma unroll
            for (int q = 0; q < 4; ++q) {
                float4 wv = wp[q];
                o[4 * q + 0] += hv * wv.x;
                o[4 * q + 1] += hv * wv.y;
                o[4 * q + 2] += hv * wv.z;
                o[4 * q + 3] += hv * wv.w;
            }
        }
        union { float4 f4; __half2 h2[4]; } p0, p1;
        #pragma unroll
        for (int q = 0; q < 4; ++q) {
            p0.h2[q] = __float22half2_rn(make_float2(o[2 * q], o[2 * q + 1]));
            p1.h2[q] = __float22half2_rn(make_float2(o[8 + 2 * q], o[8 + 2 * q + 1]));
        }
        float4* dst = (float4*)(hw + (size_t)node * F_HID + j0);
        dst[0] = p0.f4;
        dst[1] = p1.f4;
    }
}

// Layer 2 aggregation + relu + segmented global_mean_pool (pure gather).
// 8-lane groups, float4 loads, NPG=2, 8-deep edge unroll. Segment flushes ->
// block-level LDS accumulators, drained once per block.
__global__ __launch_bounds__(256) void aggpool_kernel(
        const int* __restrict__ csr_src, const int* __restrict__ row_start,
        const __half* __restrict__ hw, const float* __restrict__ dinv,
        const int* __restrict__ batch1, const int* __restrict__ batch2,
        const float* __restrict__ b2,
        float* __restrict__ pooled, float* __restrict__ cnt,
        int n, int G) {
    __shared__ float segacc[NSLOT][F_HID];
    __shared__ float segcnt[NSLOT];
    __shared__ int bb0;
    int n2 = 2 * n;
    int t = threadIdx.x;
    int block_base = blockIdx.x * (32 * NPG);   // 32 groups x NPG nodes

    for (int i = t; i < NSLOT * F_HID; i += 256) (&segacc[0][0])[i] = 0.0f;
    if (t < NSLOT) segcnt[t] = 0.0f;
    if (t == 0)
        bb0 = (block_base < n) ? batch1[block_base] : (batch2[block_base - n] + G);
    __syncthreads();
    int b0 = bb0;

    int g8 = t >> 3, lane8 = t & 7;
    int base = block_base + g8 * NPG;
    if (base < n2) {
        int end_n = base + NPG; if (end_n > n2) end_n = n2;
        const float4 bias0 = *(const float4*)(b2 + lane8 * 8);
        const float4 bias1 = *(const float4*)(b2 + lane8 * 8 + 4);
        float4 pacc0 = make_float4(0.f, 0.f, 0.f, 0.f);
        float4 pacc1 = make_float4(0.f, 0.f, 0.f, 0.f);
        float count = 0.0f;
        int cur_b = (base < n) ? batch1[base] : (batch2[base - n] + G);

        for (int node = base; node < end_n; ++node) {
            int b = (node < n) ? batch1[node] : (batch2[node - n] + G);
            if (b != cur_b) {
                int slot = cur_b - b0;
                if (slot < NSLOT) {
                    float* sp = &segacc[slot][lane8 * 8];
                    atomicAdd(sp + 0, pacc0.x); atomicAdd(sp + 1, pacc0.y);
                    atomicAdd(sp + 2, pacc0.z); atomicAdd(sp + 3, pacc0.w);
                    atomicAdd(sp + 4, pacc1.x); atomicAdd(sp + 5, pacc1.y);
                    atomicAdd(sp + 6, pacc1.z); atomicAdd(sp + 7, pacc1.w);
                    if (lane8 == 0) atomicAdd(&segcnt[slot], count);
                } else {
                    float* pp = pooled + (size_t)cur_b * F_HID + lane8 * 8;
                    atomicAdd(pp + 0, pacc0.x); atomicAdd(pp + 1, pacc0.y);
                    atomicAdd(pp + 2, pacc0.z); atomicAdd(pp + 3, pacc0.w);
                    atomicAdd(pp + 4, pacc1.x); atomicAdd(pp + 5, pacc1.y);
                    atomicAdd(pp + 6, pacc1.z); atomicAdd(pp + 7, pacc1.w);
                    if (lane8 == 0) atomicAdd(&cnt[cur_b], count);
                }
                pacc0 = make_float4(0.f, 0.f, 0.f, 0.f);
                pacc1 = make_float4(0.f, 0.f, 0.f, 0.f);
                count = 0.0f; cur_b = b;
            }
            int start = row_start[node], end = row_start[node + 1];
            float4 a0 = make_float4(0.f, 0.f, 0.f, 0.f);
            float4 a1 = make_float4(0.f, 0.f, 0.f, 0.f);
            int e = start;
            for (; e + 8 <= end; e += 8) {
                int i0 = csr_src[e + 0], i1 = csr_src[e + 1];
                int i2 = csr_src[e + 2], i3 = csr_src[e + 3];
                int i4 = csr_src[e + 4], i5 = csr_src[e + 5];
                int i6 = csr_src[e + 6], i7 = csr_src[e + 7];
                float4 r0 = *(const float4*)(hw + (size_t)i0 * F_HID + lane8 * 8);
                float4 r1 = *(const float4*)(hw + (size_t)i1 * F_HID + lane8 * 8);
                float4 r2 = *(const float4*)(hw + (size_t)i2 * F_HID + lane8 * 8);
                float4 r3 = *(const float4*)(hw + (size_t)i3 * F_HID + lane8 * 8);
                float4 r4 = *(const float4*)(hw + (size_t)i4 * F_HID + lane8 * 8);
                float4 r5 = *(const float4*)(hw + (size_t)i5 * F_HID + lane8 * 8);
                float4 r6 = *(const float4*)(hw + (size_t)i6 * F_HID + lane8 * 8);
                float4 r7 = *(const float4*)(hw + (size_t)i7 * F_HID + lane8 * 8);
                acc_row4(a0, a1, r0); acc_row4(a0, a1, r1);
                acc_row4(a0, a1, r2); acc_row4(a0, a1, r3);
                acc_row4(a0, a1, r4); acc_row4(a0, a1, r5);
                acc_row4(a0, a1, r6); acc_row4(a0, a1, r7);
            }
            for (; e + 4 <= end; e += 4) {
                int i0 = csr_src[e + 0], i1 = csr_src[e + 1];
                int i2 = csr_src[e + 2], i3 = csr_src[e + 3];
                float4 r0 = *(const float4*)(hw + (size_t)i0 * F_HID + lane8 * 8);
                float4 r1 = *(const float4*)(hw + (size_t)i1 * F_HID + lane8 * 8);
                float4 r2 = *(const float4*)(hw + (size_t)i2 * F_HID + lane8 * 8);
                float4 r3 = *(const float4*)(hw + (size_t)i3 * F_HID + lane8 * 8);
                acc_row4(a0, a1, r0); acc_row4(a0, a1, r1);
                acc_row4(a0, a1, r2); acc_row4(a0, a1, r3);
            }
            for (; e < end; ++e) {
                float4 r0 = *(const float4*)(hw + (size_t)csr_src[e] * F_HID + lane8 * 8);
                acc_row4(a0, a1, r0);
            }
            float4 rs = *(const float4*)(hw + (size_t)node * F_HID + lane8 * 8);
            acc_row4(a0, a1, rs);
            float di = dinv[node];
            pacc0.x += fmaxf(bias0.x + di * a0.x, 0.0f);
            pacc0.y += fmaxf(bias0.y + di * a0.y, 0.0f);
            pacc0.z += fmaxf(bias0.z + di * a0.z, 0.0f);
            pacc0.w += fmaxf(bias0.w + di * a0.w, 0.0f);
            pacc1.x += fmaxf(bias1.x + di * a1.x, 0.0f);
            pacc1.y += fmaxf(bias1.y + di * a1.y, 0.0f);
            pacc1.z += fmaxf(bias1.z + di * a1.z, 0.0f);
            pacc1.w += fmaxf(bias1.w + di * a1.w, 0.0f);
            count += 1.0f;
        }
        {
            int slot = cur_b - b0;
            if (slot < NSLOT) {
                float* sp = &segacc[slot][lane8 * 8];
                atomicAdd(sp + 0, pacc0.x); atomicAdd(sp + 1, pacc0.y);
                atomicAdd(sp + 2, pacc0.z); atomicAdd(sp + 3, pacc0.w);
                atomicAdd(sp + 4, pacc1.x); atomicAdd(sp + 5, pacc1.y);
                atomicAdd(sp + 6, pacc1.z); atomicAdd(sp + 7, pacc1.w);
                if (lane8 == 0) atomicAdd(&segcnt[slot], count);
            } else {
                float* pp = pooled + (size_t)cur_b * F_HID + lane8 * 8;
                atomicAdd(pp + 0, pacc0.x); atomicAdd(pp + 1, pacc0.y);
                atomicAdd(pp + 2, pacc0.z); atomicAdd(pp + 3, pacc0.w);
                atomicAdd(pp + 4, pacc1.x); atomicAdd(pp + 5, pacc1.y);
                atomicAdd(pp + 6, pacc1.z); atomicAdd(pp + 7, pacc1.w);
                if (lane8 == 0) atomicAdd(&cnt[cur_b], count);
            }
        }
    }
    __syncthreads();
    int s0 = t >> 6, l64 = t & 63;
    #pragma unroll
    for (int ss = s0; ss < NSLOT; ss += 4) {
        int seg = b0 + ss;
        if (seg < 2 * G) {
            float v = segacc[ss][l64];
            if (v != 0.0f) atomicAdd(&pooled[(size_t)seg * F_HID + l64], v);
            if (l64 == 0) {
                float c = segcnt[ss];
                if (c != 0.0f) atomicAdd(&cnt[seg], c);
            }
        }
    }
}

// per graph: combined[128] -> relu(@Wf1 + bf1)[64] -> @Wf2 + bf2 -> out[2]
__global__ void head_kernel(const float* __restrict__ p1, const float* __restrict__ c1,
                            const float* __restrict__ p2, const float* __restrict__ c2,
                            const float* __restrict__ Wf1, const float* __restrict__ bf1,
                            const float* __restrict__ Wf2, const float* __restrict__ bf2,
                            float* __restrict__ out) {
    int g = blockIdx.x;
    int j = threadIdx.x;  // 64 threads, one wave
    __shared__ float comb[128];
    float inv1 = 1.0f / fmaxf(c1[g], 1.0f);
    float inv2 = 1.0f / fmaxf(c2[g], 1.0f);
    comb[j] = p1[g * 64 + j] * inv1;
    comb[64 + j] = p2[g * 64 + j] * inv2;
    __syncthreads();
    float acc = bf1[j];
    #pragma unroll
    for (int k = 0; k < 128; ++k) acc += comb[k] * Wf1[k * 64 + j];
    float h = fmaxf(acc, 0.0f);
    float o0 = h * Wf2[j * 2 + 0];
    float o1 = h * Wf2[j * 2 + 1];
    #pragma unroll
    for (int off = 32; off > 0; off >>= 1) {
        o0 += __shfl_down(o0, off);
        o1 += __shfl_down(o1, off);
    }
    if (j == 0) {
        out[g * 2 + 0] = o0 + bf2[0];
        out[g * 2 + 1] = o1 + bf2[1];
    }
}

extern "C" void kernel_launch(void* const* d_in, const int* in_sizes, int n_in,
                              void* d_out, int out_size, void* d_ws, size_t ws_size,
                              hipStream_t stream) {
    const float* x1     = (const float*)d_in[0];
    const int*   ei1    = (const int*)d_in[1];
    const int*   batch1 = (const int*)d_in[2];
    const float* x2     = (const float*)d_in[3];
    const int*   ei2    = (const int*)d_in[4];
    const int*   batch2 = (const int*)d_in[5];
    const float* W1     = (const float*)d_in[6];
    const float* b1     = (const float*)d_in[7];
    const float* W2     = (const float*)d_in[8];
    const float* b2     = (const float*)d_in[9];
    const float* Wf1    = (const float*)d_in[10];
    const float* bf1    = (const float*)d_in[11];
    const float* Wf2    = (const float*)d_in[12];
    const float* bf2    = (const float*)d_in[13];
    float* out = (float*)d_out;

    const int n = in_sizes[0] / F_IN;   // 100000
    const int E = in_sizes[1] / 2;      // 1600000
    const int G = out_size / 2;         // 256
    const int n2 = 2 * n;
    const int E2 = 2 * E;
    const int NBK = (n2 + BKN - 1) / BKN;         // coarse buckets (196)
    const int nblkA = (E2 + EPB - 1) / EPB;       // radix blocks (782)
    const int N_A = NBK * nblkA;                  // count-matrix entries
    const int nbA = (N_A + SCAN_CHUNK - 1) / SCAN_CHUNK;

    char* ws = (char*)d_ws;
    size_t off = 0;
    unsigned* count  = (unsigned*)(ws + off); off += (((size_t)N_A + 63) & ~63ull) * 4;
    unsigned* bsumA  = (unsigned*)(ws + off); off += (size_t)((nbA + 63) & ~63) * 4;
    int* row_start   = (int*)(ws + off);      off += (((size_t)n2 + 64) & ~63ull) * 4;
    int* csr_src     = (int*)(ws + off);      off += (size_t)E2 * 4;
    float* dinv      = (float*)(ws + off);    off += (size_t)n2 * 4;
    __half* xs       = (__half*)(ws + off);   off += (size_t)n2 * F_IN * 2;
    __half* hwbuf    = (__half*)(ws + off);   off += (size_t)n2 * F_HID * 2;
    float* pooled    = (float*)(ws + off);    off += 2 * (size_t)G * F_HID * 4;
    float* cnt       = (float*)(ws + off);    off += 2 * (size_t)G * 4;

    // pairs (E2 u32 = 12.8 MB) aliases hwbuf (25.6 MB): consumed by bucketB
    // before aggmlp writes hw. Stream-ordered -> safe.
    unsigned* pairs = (unsigned*)hwbuf;

    hipMemsetAsync(pooled, 0, (2 * (size_t)G * F_HID + 2 * (size_t)G) * sizeof(float), stream);

    histA_kernel<<<nblkA, 256, 0, stream>>>(ei1, ei2, E, n, count, nblkA, NBK, E2);
    scan1_kernel<<<nbA, 256, 0, stream>>>(count, bsumA, N_A);
    scan2_kernel<<<1, 64, 0, stream>>>(bsumA, nbA);
    scan3g_kernel<<<nbA, 256, 0, stream>>>(count, bsumA, N_A);
    passA2_kernel<<<nblkA, 256, 0, stream>>>(ei1, ei2, E, n, count, pairs, nblkA, NBK, E2);
    bucketB_kernel<<<NBK, 256, 0, stream>>>(pairs, count, x1, x2, row_start, dinv, xs,
                                            csr_src, n, n2, E2, nblkA, NBK);

    aggmlp_kernel<<<(n2 + 63) / 64, 256, 0, stream>>>(csr_src, row_start, xs, dinv,
                                                      W1, b1, W2, hwbuf, n2);

    const int groups = (n2 + NPG - 1) / NPG;
    aggpool_kernel<<<(groups + 31) / 32, 256, 0, stream>>>(
        csr_src, row_start, hwbuf, dinv, batch1, batch2, b2, pooled, cnt, n, G);

    head_kernel<<<G, 64, 0, stream>>>(pooled, cnt, pooled + (size_t)G * F_HID, cnt + G,
                                      Wf1, bf1, Wf2, bf2, out);
}

// Round 13
// 269.042 us; speedup vs baseline: 1.6186x; 1.0273x over previous
//
#include <hip/hip_runtime.h>
#include <hip/hip_fp16.h>

#define F_IN 16
#define F_HID 64
#define NPG 2            // nodes per 8-lane group in aggpool
#define NSLOT 4          // LDS segment slots per block (fallback: global atomics)
#define SCAN_CHUNK 1024
#define EPB 8192         // edges per radix block
#define BKN 1024         // nodes per coarse bucket (rel = 10 bits)

// Combined problem: both graphs concatenated. Node j in [0,2n): graph g=j/n.
// Edge e in [0,2E): graph g=e/E. Segment id = batch[g][..] + g*G.
// pairs word = (rel10 << 18) | src18   (2n = 200000 < 2^18)

// E and E2 are multiples of 4 (E = 1.6M), so int4 edge loads never straddle.
__device__ inline void load_edge4(const int* __restrict__ ei1, const int* __restrict__ ei2,
                                  int E, int n, int e4, int4& s4, int4& d4) {
    if (e4 < E) {
        s4 = *(const int4*)(ei1 + e4);
        d4 = *(const int4*)(ei1 + E + e4);
    } else {
        int eb = e4 - E;
        s4 = *(const int4*)(ei2 + eb);
        d4 = *(const int4*)(ei2 + E + eb);
        s4.x += n; s4.y += n; s4.z += n; s4.w += n;
        d4.x += n; d4.y += n; d4.z += n; d4.w += n;
    }
}

// ---- radix CSR build (no global atomics) ----------------------------------

// Pass A.1: per-block LDS histogram over coarse buckets -> count[bucket][blk]
__global__ void histA_kernel(const int* __restrict__ ei1, const int* __restrict__ ei2,
                             int E, int n, unsigned* __restrict__ count,
                             int nblkA, int NBK, int E2) {
    __shared__ unsigned hist[256];   // NBK <= 256
    for (int i = threadIdx.x; i < NBK; i += 256) hist[i] = 0;
    __syncthreads();
    int base = blockIdx.x * EPB;
    #pragma unroll
    for (int r = 0; r < EPB / 1024; ++r) {
        int e4 = base + r * 1024 + threadIdx.x * 4;
        if (e4 + 4 <= E2) {
            int4 s4, d4;
            load_edge4(ei1, ei2, E, n, e4, s4, d4);
            atomicAdd(&hist[d4.x >> 10], 1u);
            atomicAdd(&hist[d4.y >> 10], 1u);
            atomicAdd(&hist[d4.z >> 10], 1u);
            atomicAdd(&hist[d4.w >> 10], 1u);
        } else if (e4 < E2) {
            for (int e = e4; e < E2; ++e) {
                int d = (e < E) ? ei1[E + e] : (ei2[e] + n);
                atomicAdd(&hist[d >> 10], 1u);
            }
        }
    }
    __syncthreads();
    for (int i = threadIdx.x; i < NBK; i += 256)
        count[(size_t)i * nblkA + blockIdx.x] = hist[i];
}

__global__ void scan1_kernel(const unsigned* __restrict__ a, unsigned* __restrict__ bsum, int N) {
    __shared__ unsigned s[256];
    int base = blockIdx.x * SCAN_CHUNK;
    unsigned t = 0;
    for (int i = threadIdx.x; i < SCAN_CHUNK; i += 256) {
        int idx = base + i;
        if (idx < N) t += a[idx];
    }
    s[threadIdx.x] = t;
    __syncthreads();
    for (int o = 128; o > 0; o >>= 1) {
        if (threadIdx.x < o) s[threadIdx.x] += s[threadIdx.x + o];
        __syncthreads();
    }
    if (threadIdx.x == 0) bsum[blockIdx.x] = s[0];
}

__global__ void scan2_kernel(unsigned* __restrict__ bsum, int nb) {
    if (threadIdx.x == 0 && blockIdx.x == 0) {
        unsigned run = 0;
        for (int i = 0; i < nb; ++i) { unsigned v = bsum[i]; bsum[i] = run; run += v; }
    }
}

// generic in-place exclusive scan finalize
__global__ void scan3g_kernel(unsigned* __restrict__ a, const unsigned* __restrict__ bsum, int N) {
    __shared__ unsigned s[256];
    int tid = threadIdx.x;
    int base = blockIdx.x * SCAN_CHUNK;
    unsigned loc[4];
    unsigned t = 0;
    #pragma unroll
    for (int j = 0; j < 4; ++j) {
        int idx = base + tid * 4 + j;
        loc[j] = (idx < N) ? a[idx] : 0u;
        t += loc[j];
    }
    s[tid] = t;
    __syncthreads();
    for (int o = 1; o < 256; o <<= 1) {
        unsigned v = (tid >= o) ? s[tid - o] : 0u;
        __syncthreads();
        s[tid] += v;
        __syncthreads();
    }
    unsigned off = bsum[blockIdx.x] + s[tid] - t;
    #pragma unroll
    for (int j = 0; j < 4; ++j) {
        int idx = base + tid * 4 + j;
        if (idx < N) a[idx] = off;
        off += loc[j];
    }
}

// Pass A.2: place edges into pairs via LDS cursors (per-(block,bucket) runs
// are consecutive -> near-line-sized writes, zero global atomics).
__global__ void passA2_kernel(const int* __restrict__ ei1, const int* __restrict__ ei2,
                              int E, int n, const unsigned* __restrict__ cbase,
                              unsigned* __restrict__ pairs, int nblkA, int NBK, int E2) {
    __shared__ unsigned cur[256];
    for (int i = threadIdx.x; i < NBK; i += 256)
        cur[i] = cbase[(size_t)i * nblkA + blockIdx.x];
    __syncthreads();
    int base = blockIdx.x * EPB;
    #pragma unroll
    for (int r = 0; r < EPB / 1024; ++r) {
        int e4 = base + r * 1024 + threadIdx.x * 4;
        if (e4 + 4 <= E2) {
            int4 s4, d4;
            load_edge4(ei1, ei2, E, n, e4, s4, d4);
            unsigned p;
            p = atomicAdd(&cur[d4.x >> 10], 1u);
            pairs[p] = ((unsigned)(d4.x & 1023) << 18) | (unsigned)s4.x;
            p = atomicAdd(&cur[d4.y >> 10], 1u);
            pairs[p] = ((unsigned)(d4.y & 1023) << 18) | (unsigned)s4.y;
            p = atomicAdd(&cur[d4.z >> 10], 1u);
            pairs[p] = ((unsigned)(d4.z & 1023) << 18) | (unsigned)s4.z;
            p = atomicAdd(&cur[d4.w >> 10], 1u);
            pairs[p] = ((unsigned)(d4.w & 1023) << 18) | (unsigned)s4.w;
        } else if (e4 < E2) {
            for (int e = e4; e < E2; ++e) {
                int s = (e < E) ? ei1[e] : (ei2[e - E] + n);
                int d = (e < E) ? ei1[E + e] : (ei2[e] + n);
                unsigned p = atomicAdd(&cur[d >> 10], 1u);
                pairs[p] = ((unsigned)(d & 1023) << 18) | (unsigned)s;
            }
        }
    }
}

// Pass B: one block per bucket. From pairs: per-node degree (LDS), block scan
// -> row_start + dinv + prescaled fp16 xs; then place csr_src via LDS cursors.
__global__ void bucketB_kernel(const unsigned* __restrict__ pairs,
                               const unsigned* __restrict__ cbase,
                               const float* __restrict__ x1, const float* __restrict__ x2,
                               int* __restrict__ row_start, float* __restrict__ dinv,
                               __half* __restrict__ xs, int* __restrict__ csr_src,
                               int n, int n2, int E2, int nblkA, int NBK) {
    __shared__ unsigned cnt[BKN];
    __shared__ int cur[BKN];
    __shared__ unsigned s[256];
    int b = blockIdx.x;
    int nodebase = b * BKN;
    int nn = n2 - nodebase; if (nn > BKN) nn = BKN;
    unsigned begin = cbase[(size_t)b * nblkA];
    unsigned end = (b + 1 < NBK) ? cbase[(size_t)(b + 1) * nblkA] : (unsigned)E2;
    int t = threadIdx.x;

    for (int i = t; i < BKN; i += 256) cnt[i] = 0;
    __syncthreads();
    for (unsigned i = begin + t; i < end; i += 256)
        atomicAdd(&cnt[pairs[i] >> 18], 1u);
    __syncthreads();

    unsigned loc[4];
    unsigned tot = 0;
    #pragma unroll
    for (int j = 0; j < 4; ++j) { loc[j] = cnt[t * 4 + j]; tot += loc[j]; }
    s[t] = tot;
    __syncthreads();
    for (int o = 1; o < 256; o <<= 1) {
        unsigned v = (t >= o) ? s[t - o] : 0u;
        __syncthreads();
        s[t] += v;
        __syncthreads();
    }
    unsigned off = begin + s[t] - tot;
    #pragma unroll
    for (int j = 0; j < 4; ++j) {
        int i = t * 4 + j;
        if (i < nn) {
            int node = nodebase + i;
            row_start[node] = (int)off;
            cur[i] = (int)off;
            float di = rsqrtf((float)loc[j] + 1.0f);
            dinv[node] = di;
            const float* xr = (node < n) ? (x1 + (size_t)node * F_IN)
                                         : (x2 + (size_t)(node - n) * F_IN);
            const float4* xin = (const float4*)xr;
            union { float4 f4; __half2 h2[4]; } u;
            __half2* xo = (__half2*)(xs + (size_t)node * F_IN);
            #pragma unroll
            for (int c = 0; c < 2; ++c) {
                float4 v0 = xin[2 * c], v1 = xin[2 * c + 1];
                u.h2[0] = __float22half2_rn(make_float2(v0.x * di, v0.y * di));
                u.h2[1] = __float22half2_rn(make_float2(v0.z * di, v0.w * di));
                u.h2[2] = __float22half2_rn(make_float2(v1.x * di, v1.y * di));
                u.h2[3] = __float22half2_rn(make_float2(v1.z * di, v1.w * di));
                *(float4*)(xo + 4 * c) = u.f4;
            }
        }
        off += loc[j];
    }
    __syncthreads();
    for (unsigned i = begin + t; i < end; i += 256) {
        unsigned v = pairs[i];
        int pos = atomicAdd(&cur[v >> 18], 1);
        csr_src[pos] = (int)(v & 0x3FFFFu);
    }
    if (b == 0 && t == 0) row_start[n2] = E2;
}

// ---- fused gather+MLP / pool ----------------------------------------------

__device__ inline void acc_row2(float4& a, float2 r) {
    union { float2 f2; __half2 h2[2]; } u; u.f2 = r;
    float2 lo = __half22float2(u.h2[0]), hi = __half22float2(u.h2[1]);
    a.x += lo.x; a.y += lo.y; a.z += hi.x; a.w += hi.y;
}

__device__ inline void acc_row4(float4& a0, float4& a1, float4 r) {
    union { float4 f4; __half2 h2[4]; } u; u.f4 = r;
    float2 p0 = __half22float2(u.h2[0]), p1 = __half22float2(u.h2[1]);
    float2 p2 = __half22float2(u.h2[2]), p3 = __half22float2(u.h2[3]);
    a0.x += p0.x; a0.y += p0.y; a0.z += p1.x; a0.w += p1.y;
    a1.x += p2.x; a1.y += p2.y; a1.z += p3.x; a1.w += p3.y;
}

// Fused layer-1 gather + dense 2-layer MLP (W2 folded):
//   xagg = dinv*(sum_s xs[s] + xs[self])          (gather, 4 lanes/node, 8-deep)
//   hw   = (relu(xagg @ W1 + b1) * dinv) @ W2     (dense, LDS weights)
__global__ __launch_bounds__(256) void aggmlp_kernel(
        const int* __restrict__ csr_src, const int* __restrict__ row_start,
        const __half* __restrict__ xs, const float* __restrict__ dinv,
        const float* __restrict__ W1, const float* __restrict__ b1,
        const float* __restrict__ W2, __half* __restrict__ hw, int n2) {
    __shared__ __align__(16) float w1[F_IN * F_HID];
    __shared__ __align__(16) float w2[F_HID * F_HID];
    __shared__ float b1s[F_HID];
    __shared__ __align__(16) float xl[64][20];
    __shared__ __align__(16) float h1s[64][68];
    int t = threadIdx.x;
    for (int i = t; i < F_IN * F_HID; i += 256) w1[i] = W1[i];
    for (int i = t; i < F_HID * F_HID; i += 256) w2[i] = W2[i];
    if (t < F_HID) b1s[t] = b1[t];

    int base = blockIdx.x * 64;
    int m = t >> 2, jg = t & 3, j0 = jg * 16;
    int node = base + m;
    bool valid = node < n2;
    float di = 0.0f;

    if (valid) {
        int start = row_start[node], end = row_start[node + 1];
        float4 a0 = make_float4(0.f, 0.f, 0.f, 0.f);
        float4 a1 = make_float4(0.f, 0.f, 0.f, 0.f);
        int e = start;
        for (; e + 8 <= end; e += 8) {
            int i0 = csr_src[e + 0], i1 = csr_src[e + 1];
            int i2 = csr_src[e + 2], i3 = csr_src[e + 3];
            int i4 = csr_src[e + 4], i5 = csr_src[e + 5];
            int i6 = csr_src[e + 6], i7 = csr_src[e + 7];
            float2 r0 = *(const float2*)(xs + (size_t)i0 * F_IN + jg * 4);
            float2 r1 = *(const float2*)(xs + (size_t)i1 * F_IN + jg * 4);
            float2 r2 = *(const float2*)(xs + (size_t)i2 * F_IN + jg * 4);
            float2 r3 = *(const float2*)(xs + (size_t)i3 * F_IN + jg * 4);
            float2 r4 = *(const float2*)(xs + (size_t)i4 * F_IN + jg * 4);
            float2 r5 = *(const float2*)(xs + (size_t)i5 * F_IN + jg * 4);
            float2 r6 = *(const float2*)(xs + (size_t)i6 * F_IN + jg * 4);
            float2 r7 = *(const float2*)(xs + (size_t)i7 * F_IN + jg * 4);
            acc_row2(a0, r0); acc_row2(a0, r1); acc_row2(a0, r2); acc_row2(a0, r3);
            acc_row2(a1, r4); acc_row2(a1, r5); acc_row2(a1, r6); acc_row2(a1, r7);
        }
        for (; e + 4 <= end; e += 4) {
            int i0 = csr_src[e + 0], i1 = csr_src[e + 1];
            int i2 = csr_src[e + 2], i3 = csr_src[e + 3];
            float2 r0 = *(const float2*)(xs + (size_t)i0 * F_IN + jg * 4);
            float2 r1 = *(const float2*)(xs + (size_t)i1 * F_IN + jg * 4);
            float2 r2 = *(const float2*)(xs + (size_t)i2 * F_IN + jg * 4);
            float2 r3 = *(const float2*)(xs + (size_t)i3 * F_IN + jg * 4);
            acc_row2(a0, r0); acc_row2(a0, r1); acc_row2(a0, r2); acc_row2(a0, r3);
        }
        for (; e < end; ++e) {
            float2 r0 = *(const float2*)(xs + (size_t)csr_src[e] * F_IN + jg * 4);
            acc_row2(a0, r0);
        }
        float2 rs = *(const float2*)(xs + (size_t)node * F_IN + jg * 4);
        acc_row2(a0, rs);
        a0.x += a1.x; a0.y += a1.y; a0.z += a1.z; a0.w += a1.w;
        di = dinv[node];
        *(float4*)&xl[m][jg * 4] =
            make_float4(a0.x * di, a0.y * di, a0.z * di, a0.w * di);
    }
    __syncthreads();

    float acc[16];
    #pragma unroll
    for (int jj = 0; jj < 16; ++jj) acc[jj] = 0.0f;
    if (valid) {
        #pragma unroll
        for (int k = 0; k < F_IN; ++k) {
            float xv = xl[m][k];
            const float4* wp = (const float4*)(w1 + k * F_HID + j0);
            #pragma unroll
            for (int q = 0; q < 4; ++q) {
                float4 wv = wp[q];
                acc[4 * q + 0] += xv * wv.x;
                acc[4 * q + 1] += xv * wv.y;
                acc[4 * q + 2] += xv * wv.z;
                acc[4 * q + 3] += xv * wv.w;
            }
        }
        #pragma unroll
        for (int jj = 0; jj < 16; ++jj)
            h1s[m][j0 + jj] = fmaxf(acc[jj] + b1s[j0 + jj], 0.0f) * di;
    }
    __syncthreads();

    float o[16];
    #pragma unroll
    for (int jj = 0; jj < 16; ++jj) o[jj] = 0.0f;
    if (valid) {
        #pragma unroll 8
        for (int k = 0; k < F_HID; ++k) {
            float hv = h1s[m][k];
            const float4* wp = (const float4*)(w2 + k * F_HID + j0);
            #pragma unroll
            for (int q = 0; q < 4; ++q) {
                float4 wv = wp[q];
                o[4 * q + 0] += hv * wv.x;
                o[4 * q + 1] += hv * wv.y;
                o[4 * q + 2] += hv * wv.z;
                o[4 * q + 3] += hv * wv.w;
            }
        }
        union { float4 f4; __half2 h2[4]; } p0, p1;
        #pragma unroll
        for (int q = 0; q < 4; ++q) {
            p0.h2[q] = __float22half2_rn(make_float2(o[2 * q], o[2 * q + 1]));
            p1.h2[q] = __float22half2_rn(make_float2(o[8 + 2 * q], o[8 + 2 * q + 1]));
        }
        float4* dst = (float4*)(hw + (size_t)node * F_HID + j0);
        dst[0] = p0.f4;
        dst[1] = p1.f4;
    }
}

// Layer 2 aggregation + relu + segmented global_mean_pool (pure gather).
// 128-thread blocks: 16 groups x 8 lanes, NPG=2 (32 nodes/block) -> finer
// tail granularity. float4 loads, 8-deep unroll. Segment flushes -> LDS
// accumulators (NSLOT=4), drained once per block.
__global__ __launch_bounds__(128) void aggpool_kernel(
        const int* __restrict__ csr_src, const int* __restrict__ row_start,
        const __half* __restrict__ hw, const float* __restrict__ dinv,
        const int* __restrict__ batch1, const int* __restrict__ batch2,
        const float* __restrict__ b2,
        float* __restrict__ pooled, float* __restrict__ cnt,
        int n, int G) {
    __shared__ float segacc[NSLOT][F_HID];
    __shared__ float segcnt[NSLOT];
    __shared__ int bb0;
    int n2 = 2 * n;
    int t = threadIdx.x;
    int block_base = blockIdx.x * (16 * NPG);   // 16 groups x NPG nodes

    for (int i = t; i < NSLOT * F_HID; i += 128) (&segacc[0][0])[i] = 0.0f;
    if (t < NSLOT) segcnt[t] = 0.0f;
    if (t == 0)
        bb0 = (block_base < n) ? batch1[block_base] : (batch2[block_base - n] + G);
    __syncthreads();
    int b0 = bb0;

    int g8 = t >> 3, lane8 = t & 7;
    int base = block_base + g8 * NPG;
    if (base < n2) {
        int end_n = base + NPG; if (end_n > n2) end_n = n2;
        const float4 bias0 = *(const float4*)(b2 + lane8 * 8);
        const float4 bias1 = *(const float4*)(b2 + lane8 * 8 + 4);
        float4 pacc0 = make_float4(0.f, 0.f, 0.f, 0.f);
        float4 pacc1 = make_float4(0.f, 0.f, 0.f, 0.f);
        float count = 0.0f;
        int cur_b = (base < n) ? batch1[base] : (batch2[base - n] + G);

        for (int node = base; node < end_n; ++node) {
            int b = (node < n) ? batch1[node] : (batch2[node - n] + G);
            if (b != cur_b) {
                int slot = cur_b - b0;
                if (slot < NSLOT) {
                    float* sp = &segacc[slot][lane8 * 8];
                    atomicAdd(sp + 0, pacc0.x); atomicAdd(sp + 1, pacc0.y);
                    atomicAdd(sp + 2, pacc0.z); atomicAdd(sp + 3, pacc0.w);
                    atomicAdd(sp + 4, pacc1.x); atomicAdd(sp + 5, pacc1.y);
                    atomicAdd(sp + 6, pacc1.z); atomicAdd(sp + 7, pacc1.w);
                    if (lane8 == 0) atomicAdd(&segcnt[slot], count);
                } else {
                    float* pp = pooled + (size_t)cur_b * F_HID + lane8 * 8;
                    atomicAdd(pp + 0, pacc0.x); atomicAdd(pp + 1, pacc0.y);
                    atomicAdd(pp + 2, pacc0.z); atomicAdd(pp + 3, pacc0.w);
                    atomicAdd(pp + 4, pacc1.x); atomicAdd(pp + 5, pacc1.y);
                    atomicAdd(pp + 6, pacc1.z); atomicAdd(pp + 7, pacc1.w);
                    if (lane8 == 0) atomicAdd(&cnt[cur_b], count);
                }
                pacc0 = make_float4(0.f, 0.f, 0.f, 0.f);
                pacc1 = make_float4(0.f, 0.f, 0.f, 0.f);
                count = 0.0f; cur_b = b;
            }
            int start = row_start[node], end = row_start[node + 1];
            float4 a0 = make_float4(0.f, 0.f, 0.f, 0.f);
            float4 a1 = make_float4(0.f, 0.f, 0.f, 0.f);
            int e = start;
            for (; e + 8 <= end; e += 8) {
                int i0 = csr_src[e + 0], i1 = csr_src[e + 1];
                int i2 = csr_src[e + 2], i3 = csr_src[e + 3];
                int i4 = csr_src[e + 4], i5 = csr_src[e + 5];
                int i6 = csr_src[e + 6], i7 = csr_src[e + 7];
                float4 r0 = *(const float4*)(hw + (size_t)i0 * F_HID + lane8 * 8);
                float4 r1 = *(const float4*)(hw + (size_t)i1 * F_HID + lane8 * 8);
                float4 r2 = *(const float4*)(hw + (size_t)i2 * F_HID + lane8 * 8);
                float4 r3 = *(const float4*)(hw + (size_t)i3 * F_HID + lane8 * 8);
                float4 r4 = *(const float4*)(hw + (size_t)i4 * F_HID + lane8 * 8);
                float4 r5 = *(const float4*)(hw + (size_t)i5 * F_HID + lane8 * 8);
                float4 r6 = *(const float4*)(hw + (size_t)i6 * F_HID + lane8 * 8);
                float4 r7 = *(const float4*)(hw + (size_t)i7 * F_HID + lane8 * 8);
                acc_row4(a0, a1, r0); acc_row4(a0, a1, r1);
                acc_row4(a0, a1, r2); acc_row4(a0, a1, r3);
                acc_row4(a0, a1, r4); acc_row4(a0, a1, r5);
                acc_row4(a0, a1, r6); acc_row4(a0, a1, r7);
            }
            for (; e + 4 <= end; e += 4) {
                int i0 = csr_src[e + 0], i1 = csr_src[e + 1];
                int i2 = csr_src[e + 2], i3 = csr_src[e + 3];
                float4 r0 = *(const float4*)(hw + (size_t)i0 * F_HID + lane8 * 8);
                float4 r1 = *(const float4*)(hw + (size_t)i1 * F_HID + lane8 * 8);
                float4 r2 = *(const float4*)(hw + (size_t)i2 * F_HID + lane8 * 8);
                float4 r3 = *(const float4*)(hw + (size_t)i3 * F_HID + lane8 * 8);
                acc_row4(a0, a1, r0); acc_row4(a0, a1, r1);
                acc_row4(a0, a1, r2); acc_row4(a0, a1, r3);
            }
            for (; e < end; ++e) {
                float4 r0 = *(const float4*)(hw + (size_t)csr_src[e] * F_HID + lane8 * 8);
                acc_row4(a0, a1, r0);
            }
            float4 rs = *(const float4*)(hw + (size_t)node * F_HID + lane8 * 8);
            acc_row4(a0, a1, rs);
            float di = dinv[node];
            pacc0.x += fmaxf(bias0.x + di * a0.x, 0.0f);
            pacc0.y += fmaxf(bias0.y + di * a0.y, 0.0f);
            pacc0.z += fmaxf(bias0.z + di * a0.z, 0.0f);
            pacc0.w += fmaxf(bias0.w + di * a0.w, 0.0f);
            pacc1.x += fmaxf(bias1.x + di * a1.x, 0.0f);
            pacc1.y += fmaxf(bias1.y + di * a1.y, 0.0f);
            pacc1.z += fmaxf(bias1.z + di * a1.z, 0.0f);
            pacc1.w += fmaxf(bias1.w + di * a1.w, 0.0f);
            count += 1.0f;
        }
        {
            int slot = cur_b - b0;
            if (slot < NSLOT) {
                float* sp = &segacc[slot][lane8 * 8];
                atomicAdd(sp + 0, pacc0.x); atomicAdd(sp + 1, pacc0.y);
                atomicAdd(sp + 2, pacc0.z); atomicAdd(sp + 3, pacc0.w);
                atomicAdd(sp + 4, pacc1.x); atomicAdd(sp + 5, pacc1.y);
                atomicAdd(sp + 6, pacc1.z); atomicAdd(sp + 7, pacc1.w);
                if (lane8 == 0) atomicAdd(&segcnt[slot], count);
            } else {
                float* pp = pooled + (size_t)cur_b * F_HID + lane8 * 8;
                atomicAdd(pp + 0, pacc0.x); atomicAdd(pp + 1, pacc0.y);
                atomicAdd(pp + 2, pacc0.z); atomicAdd(pp + 3, pacc0.w);
                atomicAdd(pp + 4, pacc1.x); atomicAdd(pp + 5, pacc1.y);
                atomicAdd(pp + 6, pacc1.z); atomicAdd(pp + 7, pacc1.w);
                if (lane8 == 0) atomicAdd(&cnt[cur_b], count);
            }
        }
    }
    __syncthreads();
    // drain: 2 slots in parallel (64 lanes each), 2 passes
    int s0 = t >> 6, l64 = t & 63;
    #pragma unroll
    for (int ss = s0; ss < NSLOT; ss += 2) {
        int seg = b0 + ss;
        if (seg < 2 * G) {
            float v = segacc[ss][l64];
            if (v != 0.0f) atomicAdd(&pooled[(size_t)seg * F_HID + l64], v);
            if (l64 == 0) {
                float c = segcnt[ss];
                if (c != 0.0f) atomicAdd(&cnt[seg], c);
            }
        }
    }
}

// per graph: combined[128] -> relu(@Wf1 + bf1)[64] -> @Wf2 + bf2 -> out[2]
__global__ void head_kernel(const float* __restrict__ p1, const float* __restrict__ c1,
                            const float* __restrict__ p2, const float* __restrict__ c2,
                            const float* __restrict__ Wf1, const float* __restrict__ bf1,
                            const float* __restrict__ Wf2, const float* __restrict__ bf2,
                            float* __restrict__ out) {
    int g = blockIdx.x;
    int j = threadIdx.x;  // 64 threads, one wave
    __shared__ float comb[128];
    float inv1 = 1.0f / fmaxf(c1[g], 1.0f);
    float inv2 = 1.0f / fmaxf(c2[g], 1.0f);
    comb[j] = p1[g * 64 + j] * inv1;
    comb[64 + j] = p2[g * 64 + j] * inv2;
    __syncthreads();
    float acc = bf1[j];
    #pragma unroll
    for (int k = 0; k < 128; ++k) acc += comb[k] * Wf1[k * 64 + j];
    float h = fmaxf(acc, 0.0f);
    float o0 = h * Wf2[j * 2 + 0];
    float o1 = h * Wf2[j * 2 + 1];
    #pragma unroll
    for (int off = 32; off > 0; off >>= 1) {
        o0 += __shfl_down(o0, off);
        o1 += __shfl_down(o1, off);
    }
    if (j == 0) {
        out[g * 2 + 0] = o0 + bf2[0];
        out[g * 2 + 1] = o1 + bf2[1];
    }
}

extern "C" void kernel_launch(void* const* d_in, const int* in_sizes, int n_in,
                              void* d_out, int out_size, void* d_ws, size_t ws_size,
                              hipStream_t stream) {
    const float* x1     = (const float*)d_in[0];
    const int*   ei1    = (const int*)d_in[1];
    const int*   batch1 = (const int*)d_in[2];
    const float* x2     = (const float*)d_in[3];
    const int*   ei2    = (const int*)d_in[4];
    const int*   batch2 = (const int*)d_in[5];
    const float* W1     = (const float*)d_in[6];
    const float* b1     = (const float*)d_in[7];
    const float* W2     = (const float*)d_in[8];
    const float* b2     = (const float*)d_in[9];
    const float* Wf1    = (const float*)d_in[10];
    const float* bf1    = (const float*)d_in[11];
    const float* Wf2    = (const float*)d_in[12];
    const float* bf2    = (const float*)d_in[13];
    float* out = (float*)d_out;

    const int n = in_sizes[0] / F_IN;   // 100000
    const int E = in_sizes[1] / 2;      // 1600000
    const int G = out_size / 2;         // 256
    const int n2 = 2 * n;
    const int E2 = 2 * E;
    const int NBK = (n2 + BKN - 1) / BKN;         // coarse buckets (196)
    const int nblkA = (E2 + EPB - 1) / EPB;       // radix blocks (391)
    const int N_A = NBK * nblkA;                  // count-matrix entries
    const int nbA = (N_A + SCAN_CHUNK - 1) / SCAN_CHUNK;

    char* ws = (char*)d_ws;
    size_t off = 0;
    unsigned* count  = (unsigned*)(ws + off); off += (((size_t)N_A + 63) & ~63ull) * 4;
    unsigned* bsumA  = (unsigned*)(ws + off); off += (size_t)((nbA + 63) & ~63) * 4;
    int* row_start   = (int*)(ws + off);      off += (((size_t)n2 + 64) & ~63ull) * 4;
    int* csr_src     = (int*)(ws + off);      off += (size_t)E2 * 4;
    float* dinv      = (float*)(ws + off);    off += (size_t)n2 * 4;
    __half* xs       = (__half*)(ws + off);   off += (size_t)n2 * F_IN * 2;
    __half* hwbuf    = (__half*)(ws + off);   off += (size_t)n2 * F_HID * 2;
    float* pooled    = (float*)(ws + off);    off += 2 * (size_t)G * F_HID * 4;
    float* cnt       = (float*)(ws + off);    off += 2 * (size_t)G * 4;

    // pairs (E2 u32 = 12.8 MB) aliases hwbuf (25.6 MB): consumed by bucketB
    // before aggmlp writes hw. Stream-ordered -> safe.
    unsigned* pairs = (unsigned*)hwbuf;

    hipMemsetAsync(pooled, 0, (2 * (size_t)G * F_HID + 2 * (size_t)G) * sizeof(float), stream);

    histA_kernel<<<nblkA, 256, 0, stream>>>(ei1, ei2, E, n, count, nblkA, NBK, E2);
    scan1_kernel<<<nbA, 256, 0, stream>>>(count, bsumA, N_A);
    scan2_kernel<<<1, 64, 0, stream>>>(bsumA, nbA);
    scan3g_kernel<<<nbA, 256, 0, stream>>>(count, bsumA, N_A);
    passA2_kernel<<<nblkA, 256, 0, stream>>>(ei1, ei2, E, n, count, pairs, nblkA, NBK, E2);
    bucketB_kernel<<<NBK, 256, 0, stream>>>(pairs, count, x1, x2, row_start, dinv, xs,
                                            csr_src, n, n2, E2, nblkA, NBK);

    aggmlp_kernel<<<(n2 + 63) / 64, 256, 0, stream>>>(csr_src, row_start, xs, dinv,
                                                      W1, b1, W2, hwbuf, n2);

    const int groups = (n2 + NPG - 1) / NPG;
    aggpool_kernel<<<(groups + 15) / 16, 128, 0, stream>>>(
        csr_src, row_start, hwbuf, dinv, batch1, batch2, b2, pooled, cnt, n, G);

    head_kernel<<<G, 64, 0, stream>>>(pooled, cnt, pooled + (size_t)G * F_HID, cnt + G,
                                      Wf1, bf1, Wf2, bf2, out);
}